// Round 7
// baseline (203.476 us; speedup 1.0000x reference)
//
#include <hip/hip_runtime.h>

typedef __attribute__((ext_vector_type(8))) short s16x8;
typedef __attribute__((ext_vector_type(4))) float f32x4;

#define SCALE 0.125f
#define LOG2E 1.4426950408889634f
#define QSC (SCALE * LOG2E)

__device__ inline float b2f(unsigned short u) {
    union { unsigned int i; float f; } x; x.i = ((unsigned int)u) << 16; return x.f;
}
__device__ inline unsigned short f2b(float f) {
    union { float f; unsigned int i; } x; x.f = f;
    unsigned int i = x.i;
    unsigned int r = (i + 0x7FFFu + ((i >> 16) & 1u)) >> 16;
    return (unsigned short)r;
}

// async global->LDS, 16B per lane; lds base must be wave-uniform.
typedef const __attribute__((address_space(1))) unsigned int guint;
typedef __attribute__((address_space(3))) unsigned int luint;
__device__ __forceinline__ void gll16(const void* g, void* l) {
    __builtin_amdgcn_global_load_lds((guint*)g, (luint*)l, 16, 0, 0);
}

// ---------------- f32 -> bf16 convert (x) ----------------
__global__ __launch_bounds__(256) void cvt_f32_bf16(
    const float* __restrict__ in, unsigned short* __restrict__ out) {
    int i = (blockIdx.x * 256 + threadIdx.x) * 8;
    f32x4 a = *(const f32x4*)(in + i);
    f32x4 b = *(const f32x4*)(in + i + 4);
    s16x8 o;
    o[0] = (short)f2b(a[0]); o[1] = (short)f2b(a[1]);
    o[2] = (short)f2b(a[2]); o[3] = (short)f2b(a[3]);
    o[4] = (short)f2b(b[0]); o[5] = (short)f2b(b[1]);
    o[6] = (short)f2b(b[2]); o[7] = (short)f2b(b[3]);
    *(s16x8*)(out + i) = o;
}

// ------------- transpose f32 -> bf16: in[R][C] -> out[C][R] -------------
__global__ __launch_bounds__(256) void transpose_f32_bf16(
    const float* __restrict__ in, unsigned short* __restrict__ out,
    int R, int C) {
    __shared__ unsigned short tile[64][72];
    int tc = blockIdx.x * 64, tr = blockIdx.y * 64;
    int t = threadIdx.x;
    int r = t >> 2, cq = (t & 3) * 16;
    const float* src = in + (size_t)(tr + r) * C + tc + cq;
#pragma unroll
    for (int j = 0; j < 16; j += 4) {
        f32x4 v = *(const f32x4*)(src + j);
        tile[r][cq + j]     = f2b(v[0]);
        tile[r][cq + j + 1] = f2b(v[1]);
        tile[r][cq + j + 2] = f2b(v[2]);
        tile[r][cq + j + 3] = f2b(v[3]);
    }
    __syncthreads();
    int oc = t >> 2, rq = (t & 3) * 16;
    s16x8 w0, w1;
#pragma unroll
    for (int j = 0; j < 8; j++) {
        w0[j] = (short)tile[rq + j][oc];
        w1[j] = (short)tile[rq + 8 + j][oc];
    }
    s16x8* dst = (s16x8*)(out + (size_t)(tc + oc) * R + tr + rq);
    dst[0] = w0; dst[1] = w1;
}

// ------------- transpose bf16: in[R][C] -> out[C][R] (for V^T) -------------
__global__ __launch_bounds__(256) void transpose_bf16(
    const unsigned short* __restrict__ in, unsigned short* __restrict__ out,
    int R, int C) {
    __shared__ unsigned short tile[64][72];
    int tc = blockIdx.x * 64, tr = blockIdx.y * 64;
    int t = threadIdx.x;
    int r = t >> 2, cq = (t & 3) * 16;
    const s16x8* src = (const s16x8*)(in + (size_t)(tr + r) * C + tc + cq);
    s16x8 v0 = src[0], v1 = src[1];
    *(s16x8*)&tile[r][cq] = v0;
    *(s16x8*)&tile[r][cq + 8] = v1;
    __syncthreads();
    int oc = t >> 2, rq = (t & 3) * 16;
    s16x8 w0, w1;
#pragma unroll
    for (int j = 0; j < 8; j++) {
        w0[j] = (short)tile[rq + j][oc];
        w1[j] = (short)tile[rq + 8 + j][oc];
    }
    s16x8* dst = (s16x8*)(out + (size_t)(tc + oc) * R + tr + rq);
    dst[0] = w0; dst[1] = w1;
}

// ---------------- RoPE tables from rotation matrix (f32) ----------------
__global__ __launch_bounds__(256) void rope_tables(
    const float* __restrict__ R, float* __restrict__ cosT,
    float* __restrict__ sinT) {
    int idx = blockIdx.x * 256 + threadIdx.x;  // L*32
    int l = idx >> 5, i = idx & 31;
    size_t base = (size_t)l * 4096;
    cosT[idx] = R[base + (size_t)(2 * i) * 64 + 2 * i];
    sinT[idx] = R[base + (size_t)(2 * i + 1) * 64 + 2 * i];
}

// ---- fused QKV GEMM + RoPE epilogue ----
// A[2048][2048] bf16, BT[3072][2048] bf16. Q written roped*QSC; K written
// roped (bf16) + repeated f32 outK; V plain. Rotation pairs adjacent cols
// = adjacent lanes -> shfl_xor(v,1).
__global__ __launch_bounds__(256) void gemm_qkv(
    const unsigned short* __restrict__ A, const unsigned short* __restrict__ BT,
    unsigned short* __restrict__ Qb, unsigned short* __restrict__ Kb,
    unsigned short* __restrict__ Vb, const float* __restrict__ cosT,
    const float* __restrict__ sinT, float* __restrict__ outK) {
    const int K = 2048;
    __shared__ unsigned short As[128 * 32];
    __shared__ unsigned short Bs[128 * 32];
    int t = threadIdx.x;
    int w = t >> 6, lane = t & 63, lo = lane & 15, hi = lane >> 4;
    int m0 = blockIdx.y * 128, n0 = blockIdx.x * 128;
    int wr = w >> 1, wc = w & 1;
    int srow = lane >> 2, scol = (lane & 3) * 8;

    const unsigned short* gA = A + (size_t)(m0 + w * 16 + srow) * K + scol;
    const unsigned short* gB = BT + (size_t)(n0 + w * 16 + srow) * K + scol;
    unsigned short* lA0 = &As[(w * 16) * 32];
    unsigned short* lA1 = &As[(64 + w * 16) * 32];
    unsigned short* lB0 = &Bs[(w * 16) * 32];
    unsigned short* lB1 = &Bs[(64 + w * 16) * 32];

    f32x4 acc[4][4] = {};

    for (int k0 = 0; k0 < K; k0 += 32) {
        gll16(gA + k0, lA0);
        gll16(gA + (size_t)64 * K + k0, lA1);
        gll16(gB + k0, lB0);
        gll16(gB + (size_t)64 * K + k0, lB1);
        __syncthreads();
        s16x8 af[4], bfr[4];
#pragma unroll
        for (int i = 0; i < 4; i++)
            af[i] = *(const s16x8*)&As[(wr * 64 + i * 16 + lo) * 32 + hi * 8];
#pragma unroll
        for (int j = 0; j < 4; j++)
            bfr[j] = *(const s16x8*)&Bs[(wc * 64 + j * 16 + lo) * 32 + hi * 8];
#pragma unroll
        for (int i = 0; i < 4; i++)
#pragma unroll
            for (int j = 0; j < 4; j++)
                acc[i][j] = __builtin_amdgcn_mfma_f32_16x16x32_bf16(
                    af[i], bfr[j], acc[i][j], 0, 0, 0);
        __syncthreads();
    }

    if (n0 < 2048) {  // ---- Q: rope + QSC ----
#pragma unroll
        for (int i = 0; i < 4; i++)
#pragma unroll
            for (int j = 0; j < 4; j++) {
                int colb = n0 + wc * 64 + j * 16 + lo;
                int d = colb & 63;
                float sgn = (d & 1) ? 1.0f : -1.0f;
                int ip = d >> 1;
#pragma unroll
                for (int r = 0; r < 4; r++) {
                    int row = m0 + wr * 64 + i * 16 + hi * 4 + r;
                    float v = acc[i][j][r];
                    float p = __shfl_xor(v, 1);
                    float c = cosT[row * 32 + ip], s = sinT[row * 32 + ip];
                    float o = (c * v + sgn * s * p) * QSC;
                    Qb[(size_t)row * 2048 + colb] = f2b(o);
                }
            }
    } else if (n0 < 2560) {  // ---- K: rope + repeated f32 out ----
        int cb = n0 - 2048;
#pragma unroll
        for (int i = 0; i < 4; i++)
#pragma unroll
            for (int j = 0; j < 4; j++) {
                int colb = cb + wc * 64 + j * 16 + lo;
                int d = colb & 63;
                int kvh2 = colb >> 6;
                float sgn = (d & 1) ? 1.0f : -1.0f;
                int ip = d >> 1;
#pragma unroll
                for (int r = 0; r < 4; r++) {
                    int row = m0 + wr * 64 + i * 16 + hi * 4 + r;
                    float v = acc[i][j][r];
                    float p = __shfl_xor(v, 1);
                    float c = cosT[row * 32 + ip], s = sinT[row * 32 + ip];
                    float o = c * v + sgn * s * p;
                    Kb[(size_t)row * 512 + colb] = f2b(o);
#pragma unroll
                    for (int rep = 0; rep < 4; rep++) {
                        int h2 = kvh2 * 4 + rep;
                        outK[((size_t)h2 * 2048 + row) * 64 + d] = o;
                    }
                }
            }
    } else {  // ---- V: plain ----
        int cb = n0 - 2560;
#pragma unroll
        for (int i = 0; i < 4; i++)
#pragma unroll
            for (int j = 0; j < 4; j++)
#pragma unroll
                for (int r = 0; r < 4; r++) {
                    int row = m0 + wr * 64 + i * 16 + hi * 4 + r;
                    int col = cb + wc * 64 + j * 16 + lo;
                    Vb[(size_t)row * 512 + col] = f2b(acc[i][j][r]);
                }
    }
}

// -------- output GEMM: A[M][K] bf16, BT[N][K] bf16 -> C[M][N] f32 --------
__global__ __launch_bounds__(256) void gemm_out(
    const unsigned short* __restrict__ A, const unsigned short* __restrict__ BT,
    float* __restrict__ C, int M, int N, int K) {
    __shared__ unsigned short As[128 * 32];
    __shared__ unsigned short Bs[128 * 32];
    int t = threadIdx.x;
    int w = t >> 6, lane = t & 63, lo = lane & 15, hi = lane >> 4;
    int m0 = blockIdx.y * 128, n0 = blockIdx.x * 128;
    int wr = w >> 1, wc = w & 1;
    int srow = lane >> 2, scol = (lane & 3) * 8;

    const unsigned short* gA = A + (size_t)(m0 + w * 16 + srow) * K + scol;
    const unsigned short* gB = BT + (size_t)(n0 + w * 16 + srow) * K + scol;
    unsigned short* lA0 = &As[(w * 16) * 32];
    unsigned short* lA1 = &As[(64 + w * 16) * 32];
    unsigned short* lB0 = &Bs[(w * 16) * 32];
    unsigned short* lB1 = &Bs[(64 + w * 16) * 32];

    f32x4 acc[4][4] = {};

    for (int k0 = 0; k0 < K; k0 += 32) {
        gll16(gA + k0, lA0);
        gll16(gA + (size_t)64 * K + k0, lA1);
        gll16(gB + k0, lB0);
        gll16(gB + (size_t)64 * K + k0, lB1);
        __syncthreads();
        s16x8 af[4], bfr[4];
#pragma unroll
        for (int i = 0; i < 4; i++)
            af[i] = *(const s16x8*)&As[(wr * 64 + i * 16 + lo) * 32 + hi * 8];
#pragma unroll
        for (int j = 0; j < 4; j++)
            bfr[j] = *(const s16x8*)&Bs[(wc * 64 + j * 16 + lo) * 32 + hi * 8];
#pragma unroll
        for (int i = 0; i < 4; i++)
#pragma unroll
            for (int j = 0; j < 4; j++)
                acc[i][j] = __builtin_amdgcn_mfma_f32_16x16x32_bf16(
                    af[i], bfr[j], acc[i][j], 0, 0, 0);
        __syncthreads();
    }
#pragma unroll
    for (int i = 0; i < 4; i++)
#pragma unroll
        for (int j = 0; j < 4; j++)
#pragma unroll
            for (int r = 0; r < 4; r++) {
                int row = m0 + wr * 64 + i * 16 + hi * 4 + r;
                int col = n0 + wc * 64 + j * 16 + lo;
                C[(size_t)row * N + col] = acc[i][j][r];
            }
}

// ---------------- V repeated f32 out ----------------
__global__ __launch_bounds__(256) void v_out(
    const unsigned short* __restrict__ V, float* __restrict__ outV) {
    int idx = blockIdx.x * 256 + threadIdx.x;  // L * 64 chunks of 8
    int l = idx >> 6, c8 = idx & 63;
    int kvh = c8 >> 3, d0 = (c8 & 7) * 8;
    s16x8 v = *(const s16x8*)(V + (size_t)l * 512 + c8 * 8);
    float f[8];
#pragma unroll
    for (int j = 0; j < 8; j++) f[j] = b2f((unsigned short)v[j]);
#pragma unroll
    for (int rep = 0; rep < 4; rep++) {
        int h = kvh * 4 + rep;
        float* dst = outV + ((size_t)h * 2048 + l) * 64 + d0;
        *(f32x4*)dst = *(f32x4*)&f[0];
        *(f32x4*)(dst + 4) = *(f32x4*)&f[4];
    }
}

// ====================== flash attention (causal) ======================
// 2 waves/block, 64 q-rows per part; each block processes the balanced
// pair (qb, 31-qb) of 64-row q-chunks -> every block = exactly 33 k-tiles.
// Grid (32 h, 16 pairs), 512 equal blocks. K/V^T tiles in LDS (double-
// buffered, gll16 staged, XOR-preswizzled source). Swapped QK^T; in-reg
// softmax with defer-max; cvt_pk + shfl repack into PV A-fragment.

__device__ __forceinline__ s16x8 repack_p(
    const unsigned int pk[4][2], int c, int src1, bool selB) {
    int src2 = src1 + 16;
    unsigned int tA0 = pk[2 * c][0], tA1 = pk[2 * c][1];
    unsigned int tB0 = pk[2 * c + 1][0], tB1 = pk[2 * c + 1][1];
    unsigned int a0 = __shfl((int)tA0, src1), a1 = __shfl((int)tA1, src1);
    unsigned int a2 = __shfl((int)tA0, src2), a3 = __shfl((int)tA1, src2);
    unsigned int b0 = __shfl((int)tB0, src1), b1 = __shfl((int)tB1, src1);
    unsigned int b2 = __shfl((int)tB0, src2), b3 = __shfl((int)tB1, src2);
    union { s16x8 v; unsigned int u[4]; } x;
    x.u[0] = selB ? b0 : a0;
    x.u[1] = selB ? b1 : a1;
    x.u[2] = selB ? b2 : a2;
    x.u[3] = selB ? b3 : a3;
    return x.v;
}

__global__ __launch_bounds__(128) void attn(
    const unsigned short* __restrict__ Q, const unsigned short* __restrict__ Kr,
    const unsigned short* __restrict__ Vt, unsigned short* __restrict__ Oa) {
    __shared__ unsigned short KL[2][64 * 64];
    __shared__ unsigned short VL[2][64 * 64];

    int h = blockIdx.x;
    int kvh = h >> 2;
    int pairid = blockIdx.y;  // 0..15
    int t = threadIdx.x, wave = t >> 6, lane = t & 63, lo = lane & 15, hi = lane >> 4;

    int sc = lane & 7;
    int src1 = lo + ((hi & 1) << 5);
    bool selB = hi >= 2;
    int swz = lo & 7;
    int qrel0 = wave * 32 + lo;  // within-diag-tile q offset, group 0

#define STAGE_KV(buf, kb)                                                      \
    {                                                                          \
        _Pragma("unroll")                                                      \
        for (int j = 0; j < 4; j++) {                                          \
            int r = wave * 32 + (lane >> 3) + j * 8;                           \
            gll16(Kr + (size_t)((kb) * 64 + r) * 512 + kvh * 64 +              \
                      ((sc ^ (r & 7)) * 8),                                    \
                  &KL[buf][(wave * 32 + j * 8) * 64]);                         \
            gll16(Vt + (size_t)(kvh * 64 + r) * 2048 + (kb) * 64 +             \
                      ((sc ^ (r & 7)) * 8),                                    \
                  &VL[buf][(wave * 32 + j * 8) * 64]);                         \
        }                                                                      \
    }

#pragma unroll 1
    for (int part = 0; part < 2; ++part) {
        int qb = part ? (31 - pairid) : pairid;  // 64-row q-chunk index
        int qw = qb * 64 + wave * 32;
        int nt = qb + 1;

        s16x8 qf[2][2];
#pragma unroll
        for (int g = 0; g < 2; g++)
#pragma unroll
            for (int hf = 0; hf < 2; hf++)
                qf[g][hf] = *(const s16x8*)(Q + (size_t)(qw + g * 16 + lo) * 2048 +
                                            h * 64 + hf * 32 + hi * 8);

        f32x4 O0[4] = {}, O1[4] = {};
        float m0 = -1e30f, m1 = -1e30f, l0 = 0.f, l1 = 0.f;

        STAGE_KV(0, 0);
        __syncthreads();

        for (int kb = 0; kb < nt; ++kb) {
            int cur = kb & 1;
            if (kb + 1 < nt) STAGE_KV(cur ^ 1, kb + 1);

            s16x8 kf[4][2];
#pragma unroll
            for (int tt = 0; tt < 4; tt++)
#pragma unroll
                for (int hf = 0; hf < 2; hf++) {
                    int ch = (hf * 4 + hi) ^ swz;
                    kf[tt][hf] = *(const s16x8*)&KL[cur][(tt * 16 + lo) * 64 + ch * 8];
                }
            s16x8 vf[2][4];
#pragma unroll
            for (int c = 0; c < 2; c++)
#pragma unroll
                for (int dt = 0; dt < 4; dt++) {
                    int ch = (c * 4 + hi) ^ swz;
                    vf[c][dt] = *(const s16x8*)&VL[cur][(dt * 16 + lo) * 64 + ch * 8];
                }

            f32x4 s0[4], s1[4];
            __builtin_amdgcn_s_setprio(1);
#pragma unroll
            for (int tt = 0; tt < 4; tt++) {
                f32x4 z0 = {}, z1 = {};
                z0 = __builtin_amdgcn_mfma_f32_16x16x32_bf16(kf[tt][0], qf[0][0], z0, 0, 0, 0);
                z0 = __builtin_amdgcn_mfma_f32_16x16x32_bf16(kf[tt][1], qf[0][1], z0, 0, 0, 0);
                z1 = __builtin_amdgcn_mfma_f32_16x16x32_bf16(kf[tt][0], qf[1][0], z1, 0, 0, 0);
                z1 = __builtin_amdgcn_mfma_f32_16x16x32_bf16(kf[tt][1], qf[1][1], z1, 0, 0, 0);
                s0[tt] = z0; s1[tt] = z1;
            }
            __builtin_amdgcn_s_setprio(0);

            if (kb == nt - 1) {  // diag tile: causal mask
#pragma unroll
                for (int tt = 0; tt < 4; tt++)
#pragma unroll
                    for (int r = 0; r < 4; r++) {
                        int kg = tt * 16 + hi * 4 + r;
                        if (kg > qrel0) s0[tt][r] = -1e30f;
                        if (kg > qrel0 + 16) s1[tt][r] = -1e30f;
                    }
            }

            // ---- online softmax with defer-max (THR = 8, log2 units) ----
            float mx0 = s0[0][0], mx1 = s1[0][0];
#pragma unroll
            for (int tt = 0; tt < 4; tt++)
#pragma unroll
                for (int r = 0; r < 4; r++) {
                    mx0 = fmaxf(mx0, s0[tt][r]);
                    mx1 = fmaxf(mx1, s1[tt][r]);
                }
            mx0 = fmaxf(mx0, __shfl_xor(mx0, 16));
            mx0 = fmaxf(mx0, __shfl_xor(mx0, 32));
            mx1 = fmaxf(mx1, __shfl_xor(mx1, 16));
            mx1 = fmaxf(mx1, __shfl_xor(mx1, 32));

            if (!__all((mx0 - m0 <= 8.0f) && (mx1 - m1 <= 8.0f))) {
                float mn0 = fmaxf(m0, mx0), mn1 = fmaxf(m1, mx1);
                float al0 = __builtin_amdgcn_exp2f(m0 - mn0);
                float al1 = __builtin_amdgcn_exp2f(m1 - mn1);
                m0 = mn0; m1 = mn1;
                l0 *= al0; l1 *= al1;
                float a0r[4], a1r[4];
#pragma unroll
                for (int r = 0; r < 4; r++) {
                    a0r[r] = __shfl(al0, hi * 4 + r);
                    a1r[r] = __shfl(al1, hi * 4 + r);
                }
#pragma unroll
                for (int dt = 0; dt < 4; dt++)
#pragma unroll
                    for (int r = 0; r < 4; r++) {
                        O0[dt][r] *= a0r[r];
                        O1[dt][r] *= a1r[r];
                    }
            }

            unsigned int pk0[4][2], pk1[4][2];
            float rs0 = 0.f, rs1 = 0.f;
#pragma unroll
            for (int tt = 0; tt < 4; tt++) {
#pragma unroll
                for (int r = 0; r < 4; r++) {
                    float p0 = __builtin_amdgcn_exp2f(s0[tt][r] - m0);
                    float p1 = __builtin_amdgcn_exp2f(s1[tt][r] - m1);
                    s0[tt][r] = p0; s1[tt][r] = p1;
                    rs0 += p0; rs1 += p1;
                }
                unsigned int a, b;
                asm("v_cvt_pk_bf16_f32 %0, %1, %2" : "=v"(a) : "v"(s0[tt][0]), "v"(s0[tt][1]));
                asm("v_cvt_pk_bf16_f32 %0, %1, %2" : "=v"(b) : "v"(s0[tt][2]), "v"(s0[tt][3]));
                pk0[tt][0] = a; pk0[tt][1] = b;
                asm("v_cvt_pk_bf16_f32 %0, %1, %2" : "=v"(a) : "v"(s1[tt][0]), "v"(s1[tt][1]));
                asm("v_cvt_pk_bf16_f32 %0, %1, %2" : "=v"(b) : "v"(s1[tt][2]), "v"(s1[tt][3]));
                pk1[tt][0] = a; pk1[tt][1] = b;
            }
            rs0 += __shfl_xor(rs0, 16);
            rs0 += __shfl_xor(rs0, 32);
            rs1 += __shfl_xor(rs1, 16);
            rs1 += __shfl_xor(rs1, 32);
            l0 += rs0; l1 += rs1;

#pragma unroll
            for (int c = 0; c < 2; c++) {
                s16x8 pa0 = repack_p(pk0, c, src1, selB);
                s16x8 pa1 = repack_p(pk1, c, src1, selB);
                __builtin_amdgcn_s_setprio(1);
#pragma unroll
                for (int dt = 0; dt < 4; dt++) {
                    O0[dt] = __builtin_amdgcn_mfma_f32_16x16x32_bf16(pa0, vf[c][dt], O0[dt], 0, 0, 0);
                    O1[dt] = __builtin_amdgcn_mfma_f32_16x16x32_bf16(pa1, vf[c][dt], O1[dt], 0, 0, 0);
                }
                __builtin_amdgcn_s_setprio(0);
            }
            __syncthreads();
        }

#pragma unroll
        for (int g = 0; g < 2; g++) {
            float lg = g ? l1 : l0;
            f32x4* O = g ? O1 : O0;
            float inv[4];
#pragma unroll
            for (int r = 0; r < 4; r++) inv[r] = 1.0f / __shfl(lg, hi * 4 + r);
            int qrow = qw + g * 16 + hi * 4;
#pragma unroll
            for (int dt = 0; dt < 4; dt++)
#pragma unroll
                for (int r = 0; r < 4; r++)
                    Oa[(size_t)(qrow + r) * 2048 + h * 64 + dt * 16 + lo] =
                        f2b(O[dt][r] * inv[r]);
        }
    }
}

extern "C" void kernel_launch(void* const* d_in, const int* in_sizes, int n_in,
                              void* d_out, int out_size, void* d_ws, size_t ws_size,
                              hipStream_t stream) {
    const float* x  = (const float*)d_in[0];
    const float* R  = (const float*)d_in[1];
    // d_in[2] = mask: unused (causal mask applied analytically)
    const float* wq = (const float*)d_in[3];
    const float* wk = (const float*)d_in[4];
    const float* wv = (const float*)d_in[5];
    const float* wo = (const float*)d_in[6];

    float* out0 = (float*)d_out;
    float* outK = out0 + (size_t)2048 * 2048;
    float* outV = outK + (size_t)32 * 2048 * 64;

    char* ws = (char*)d_ws;
    unsigned short* BTall = (unsigned short*)(ws);               // 12 MB [3072][2048]
    unsigned short* woT = (unsigned short*)(ws + 12582912);      // 8 MB
    unsigned short* Qb  = (unsigned short*)(ws + 20971520);      // 8 MB
    unsigned short* Kb  = (unsigned short*)(ws + 29360128);      // 2 MB
    unsigned short* Vb  = (unsigned short*)(ws + 31457280);      // 2 MB
    unsigned short* VtT = (unsigned short*)(ws + 33554432);      // 2 MB [512][2048]
    unsigned short* Ob  = (unsigned short*)(ws + 35651584);      // 8 MB
    float* cosT = (float*)(ws + 44040192);                       // 256 KB
    float* sinT = (float*)(ws + 44302336);                       // 256 KB
    unsigned short* xb  = (unsigned short*)(ws + 44564480);      // 8 MB

    cvt_f32_bf16<<<2048, 256, 0, stream>>>(x, xb);
    transpose_f32_bf16<<<dim3(32, 32), 256, 0, stream>>>(wq, BTall, 2048, 2048);
    transpose_f32_bf16<<<dim3(8, 32), 256, 0, stream>>>(wk, BTall + (size_t)2048 * 2048, 2048, 512);
    transpose_f32_bf16<<<dim3(8, 32), 256, 0, stream>>>(wv, BTall + (size_t)2560 * 2048, 2048, 512);
    transpose_f32_bf16<<<dim3(32, 32), 256, 0, stream>>>(wo, woT, 2048, 2048);
    rope_tables<<<256, 256, 0, stream>>>(R, cosT, sinT);

    gemm_qkv<<<dim3(24, 16), 256, 0, stream>>>(xb, BTall, Qb, Kb, Vb, cosT, sinT, outK);

    v_out<<<512, 256, 0, stream>>>(Vb, outV);
    transpose_bf16<<<dim3(8, 32), 256, 0, stream>>>(Vb, VtT, 2048, 512);

    attn<<<dim3(32, 16), 128, 0, stream>>>(Qb, Kb, VtT, Ob);

    gemm_out<<<dim3(16, 16), 256, 0, stream>>>(Ob, woT, out0, 2048, 2048, 2048);
}

// Round 8
// 195.301 us; speedup vs baseline: 1.0419x; 1.0419x over previous
//
#include <hip/hip_runtime.h>

typedef __attribute__((ext_vector_type(8))) short s16x8;
typedef __attribute__((ext_vector_type(4))) float f32x4;

#define SCALE 0.125f
#define LOG2E 1.4426950408889634f
#define QSC (SCALE * LOG2E)

__device__ inline float b2f(unsigned short u) {
    union { unsigned int i; float f; } x; x.i = ((unsigned int)u) << 16; return x.f;
}
__device__ inline unsigned short f2b(float f) {
    union { float f; unsigned int i; } x; x.f = f;
    unsigned int i = x.i;
    unsigned int r = (i + 0x7FFFu + ((i >> 16) & 1u)) >> 16;
    return (unsigned short)r;
}

// async global->LDS, 16B per lane; lds base must be wave-uniform.
typedef const __attribute__((address_space(1))) unsigned int guint;
typedef __attribute__((address_space(3))) unsigned int luint;
__device__ __forceinline__ void gll16(const void* g, void* l) {
    __builtin_amdgcn_global_load_lds((guint*)g, (luint*)l, 16, 0, 0);
}

// ---------------- f32 -> bf16 convert (x) ----------------
__global__ __launch_bounds__(256) void cvt_f32_bf16(
    const float* __restrict__ in, unsigned short* __restrict__ out) {
    int i = (blockIdx.x * 256 + threadIdx.x) * 8;
    f32x4 a = *(const f32x4*)(in + i);
    f32x4 b = *(const f32x4*)(in + i + 4);
    s16x8 o;
    o[0] = (short)f2b(a[0]); o[1] = (short)f2b(a[1]);
    o[2] = (short)f2b(a[2]); o[3] = (short)f2b(a[3]);
    o[4] = (short)f2b(b[0]); o[5] = (short)f2b(b[1]);
    o[6] = (short)f2b(b[2]); o[7] = (short)f2b(b[3]);
    *(s16x8*)(out + i) = o;
}

// ------------- transpose f32 -> bf16: in[R][C] -> out[C][R] -------------
__global__ __launch_bounds__(256) void transpose_f32_bf16(
    const float* __restrict__ in, unsigned short* __restrict__ out,
    int R, int C) {
    __shared__ unsigned short tile[64][72];
    int tc = blockIdx.x * 64, tr = blockIdx.y * 64;
    int t = threadIdx.x;
    int r = t >> 2, cq = (t & 3) * 16;
    const float* src = in + (size_t)(tr + r) * C + tc + cq;
#pragma unroll
    for (int j = 0; j < 16; j += 4) {
        f32x4 v = *(const f32x4*)(src + j);
        tile[r][cq + j]     = f2b(v[0]);
        tile[r][cq + j + 1] = f2b(v[1]);
        tile[r][cq + j + 2] = f2b(v[2]);
        tile[r][cq + j + 3] = f2b(v[3]);
    }
    __syncthreads();
    int oc = t >> 2, rq = (t & 3) * 16;
    s16x8 w0, w1;
#pragma unroll
    for (int j = 0; j < 8; j++) {
        w0[j] = (short)tile[rq + j][oc];
        w1[j] = (short)tile[rq + 8 + j][oc];
    }
    s16x8* dst = (s16x8*)(out + (size_t)(tc + oc) * R + tr + rq);
    dst[0] = w0; dst[1] = w1;
}

// ------------- transpose bf16: in[R][C] -> out[C][R] (for V^T) -------------
__global__ __launch_bounds__(256) void transpose_bf16(
    const unsigned short* __restrict__ in, unsigned short* __restrict__ out,
    int R, int C) {
    __shared__ unsigned short tile[64][72];
    int tc = blockIdx.x * 64, tr = blockIdx.y * 64;
    int t = threadIdx.x;
    int r = t >> 2, cq = (t & 3) * 16;
    const s16x8* src = (const s16x8*)(in + (size_t)(tr + r) * C + tc + cq);
    s16x8 v0 = src[0], v1 = src[1];
    *(s16x8*)&tile[r][cq] = v0;
    *(s16x8*)&tile[r][cq + 8] = v1;
    __syncthreads();
    int oc = t >> 2, rq = (t & 3) * 16;
    s16x8 w0, w1;
#pragma unroll
    for (int j = 0; j < 8; j++) {
        w0[j] = (short)tile[rq + j][oc];
        w1[j] = (short)tile[rq + 8 + j][oc];
    }
    s16x8* dst = (s16x8*)(out + (size_t)(tc + oc) * R + tr + rq);
    dst[0] = w0; dst[1] = w1;
}

// ---------------- RoPE tables from rotation matrix (f32) ----------------
__global__ __launch_bounds__(256) void rope_tables(
    const float* __restrict__ R, float* __restrict__ cosT,
    float* __restrict__ sinT) {
    int idx = blockIdx.x * 256 + threadIdx.x;  // L*32
    int l = idx >> 5, i = idx & 31;
    size_t base = (size_t)l * 4096;
    cosT[idx] = R[base + (size_t)(2 * i) * 64 + 2 * i];
    sinT[idx] = R[base + (size_t)(2 * i + 1) * 64 + 2 * i];
}

// ==== GEMM core: BM=128 x BN=64 x BK=32, 4 waves (2 row x 2 col) ====
// As[128*32] (8KB, 2 gll16/wave), Bs[64*32] (4KB, 1 gll16/wave).
// 2-3 blocks/CU -> inter-block overlap hides the per-K-step barrier drain.

// ---- fused QKV GEMM + RoPE epilogue ----
__global__ __launch_bounds__(256) void gemm_qkv(
    const unsigned short* __restrict__ A, const unsigned short* __restrict__ BT,
    unsigned short* __restrict__ Qb, unsigned short* __restrict__ Kb,
    unsigned short* __restrict__ Vb, const float* __restrict__ cosT,
    const float* __restrict__ sinT, float* __restrict__ outK) {
    const int K = 2048;
    __shared__ unsigned short As[128 * 32];
    __shared__ unsigned short Bs[64 * 32];
    int t = threadIdx.x;
    int w = t >> 6, lane = t & 63, lo = lane & 15, hi = lane >> 4;
    int m0 = blockIdx.y * 128, n0 = blockIdx.x * 64;
    int wr = w >> 1, wc = w & 1;
    int srow = lane >> 2, scol = (lane & 3) * 8;

    const unsigned short* gA = A + (size_t)(m0 + w * 16 + srow) * K + scol;
    const unsigned short* gB = BT + (size_t)(n0 + w * 16 + srow) * K + scol;
    unsigned short* lA0 = &As[(w * 16) * 32];
    unsigned short* lA1 = &As[(64 + w * 16) * 32];
    unsigned short* lB  = &Bs[(w * 16) * 32];

    f32x4 acc[4][2] = {};

    for (int k0 = 0; k0 < K; k0 += 32) {
        gll16(gA + k0, lA0);
        gll16(gA + (size_t)64 * K + k0, lA1);
        gll16(gB + k0, lB);
        __syncthreads();
        s16x8 af[4], bfr[2];
#pragma unroll
        for (int i = 0; i < 4; i++)
            af[i] = *(const s16x8*)&As[(wr * 64 + i * 16 + lo) * 32 + hi * 8];
#pragma unroll
        for (int j = 0; j < 2; j++)
            bfr[j] = *(const s16x8*)&Bs[(wc * 32 + j * 16 + lo) * 32 + hi * 8];
#pragma unroll
        for (int i = 0; i < 4; i++)
#pragma unroll
            for (int j = 0; j < 2; j++)
                acc[i][j] = __builtin_amdgcn_mfma_f32_16x16x32_bf16(
                    af[i], bfr[j], acc[i][j], 0, 0, 0);
        __syncthreads();
    }

    if (n0 < 2048) {  // ---- Q: rope + QSC ----
#pragma unroll
        for (int i = 0; i < 4; i++)
#pragma unroll
            for (int j = 0; j < 2; j++) {
                int colb = n0 + wc * 32 + j * 16 + lo;
                int d = colb & 63;
                float sgn = (d & 1) ? 1.0f : -1.0f;
                int ip = d >> 1;
#pragma unroll
                for (int r = 0; r < 4; r++) {
                    int row = m0 + wr * 64 + i * 16 + hi * 4 + r;
                    float v = acc[i][j][r];
                    float p = __shfl_xor(v, 1);
                    float c = cosT[row * 32 + ip], s = sinT[row * 32 + ip];
                    float o = (c * v + sgn * s * p) * QSC;
                    Qb[(size_t)row * 2048 + colb] = f2b(o);
                }
            }
    } else if (n0 < 2560) {  // ---- K: rope + repeated f32 out ----
        int cb = n0 - 2048;
#pragma unroll
        for (int i = 0; i < 4; i++)
#pragma unroll
            for (int j = 0; j < 2; j++) {
                int colb = cb + wc * 32 + j * 16 + lo;
                int d = colb & 63;
                int kvh2 = colb >> 6;
                float sgn = (d & 1) ? 1.0f : -1.0f;
                int ip = d >> 1;
#pragma unroll
                for (int r = 0; r < 4; r++) {
                    int row = m0 + wr * 64 + i * 16 + hi * 4 + r;
                    float v = acc[i][j][r];
                    float p = __shfl_xor(v, 1);
                    float c = cosT[row * 32 + ip], s = sinT[row * 32 + ip];
                    float o = c * v + sgn * s * p;
                    Kb[(size_t)row * 512 + colb] = f2b(o);
#pragma unroll
                    for (int rep = 0; rep < 4; rep++) {
                        int h2 = kvh2 * 4 + rep;
                        outK[((size_t)h2 * 2048 + row) * 64 + d] = o;
                    }
                }
            }
    } else {  // ---- V: plain ----
        int cb = n0 - 2560;
#pragma unroll
        for (int i = 0; i < 4; i++)
#pragma unroll
            for (int j = 0; j < 2; j++)
#pragma unroll
                for (int r = 0; r < 4; r++) {
                    int row = m0 + wr * 64 + i * 16 + hi * 4 + r;
                    int col = cb + wc * 32 + j * 16 + lo;
                    Vb[(size_t)row * 512 + col] = f2b(acc[i][j][r]);
                }
    }
}

// -------- output GEMM: A[M][K] bf16, BT[N][K] bf16 -> C[M][N] f32 --------
__global__ __launch_bounds__(256) void gemm_out(
    const unsigned short* __restrict__ A, const unsigned short* __restrict__ BT,
    float* __restrict__ C, int M, int N, int K) {
    __shared__ unsigned short As[128 * 32];
    __shared__ unsigned short Bs[64 * 32];
    int t = threadIdx.x;
    int w = t >> 6, lane = t & 63, lo = lane & 15, hi = lane >> 4;
    int m0 = blockIdx.y * 128, n0 = blockIdx.x * 64;
    int wr = w >> 1, wc = w & 1;
    int srow = lane >> 2, scol = (lane & 3) * 8;

    const unsigned short* gA = A + (size_t)(m0 + w * 16 + srow) * K + scol;
    const unsigned short* gB = BT + (size_t)(n0 + w * 16 + srow) * K + scol;
    unsigned short* lA0 = &As[(w * 16) * 32];
    unsigned short* lA1 = &As[(64 + w * 16) * 32];
    unsigned short* lB  = &Bs[(w * 16) * 32];

    f32x4 acc[4][2] = {};

    for (int k0 = 0; k0 < K; k0 += 32) {
        gll16(gA + k0, lA0);
        gll16(gA + (size_t)64 * K + k0, lA1);
        gll16(gB + k0, lB);
        __syncthreads();
        s16x8 af[4], bfr[2];
#pragma unroll
        for (int i = 0; i < 4; i++)
            af[i] = *(const s16x8*)&As[(wr * 64 + i * 16 + lo) * 32 + hi * 8];
#pragma unroll
        for (int j = 0; j < 2; j++)
            bfr[j] = *(const s16x8*)&Bs[(wc * 32 + j * 16 + lo) * 32 + hi * 8];
#pragma unroll
        for (int i = 0; i < 4; i++)
#pragma unroll
            for (int j = 0; j < 2; j++)
                acc[i][j] = __builtin_amdgcn_mfma_f32_16x16x32_bf16(
                    af[i], bfr[j], acc[i][j], 0, 0, 0);
        __syncthreads();
    }
#pragma unroll
    for (int i = 0; i < 4; i++)
#pragma unroll
        for (int j = 0; j < 2; j++)
#pragma unroll
            for (int r = 0; r < 4; r++) {
                int row = m0 + wr * 64 + i * 16 + hi * 4 + r;
                int col = n0 + wc * 32 + j * 16 + lo;
                C[(size_t)row * N + col] = acc[i][j][r];
            }
}

// ---------------- V repeated f32 out ----------------
__global__ __launch_bounds__(256) void v_out(
    const unsigned short* __restrict__ V, float* __restrict__ outV) {
    int idx = blockIdx.x * 256 + threadIdx.x;  // L * 64 chunks of 8
    int l = idx >> 6, c8 = idx & 63;
    int kvh = c8 >> 3, d0 = (c8 & 7) * 8;
    s16x8 v = *(const s16x8*)(V + (size_t)l * 512 + c8 * 8);
    float f[8];
#pragma unroll
    for (int j = 0; j < 8; j++) f[j] = b2f((unsigned short)v[j]);
#pragma unroll
    for (int rep = 0; rep < 4; rep++) {
        int h = kvh * 4 + rep;
        float* dst = outV + ((size_t)h * 2048 + l) * 64 + d0;
        *(f32x4*)dst = *(f32x4*)&f[0];
        *(f32x4*)(dst + 4) = *(f32x4*)&f[4];
    }
}

// ====================== flash attention (causal) ======================
// Round-6 structure (known 65us): 4 waves/block, 128 q-rows per block
// (32/wave, 2 q-groups per wave). K/V^T tiles in LDS, double-buffered,
// gll16-staged (linear dest + XOR-preswizzled source). Swapped QK^T;
// in-reg softmax with defer-max; cvt_pk + shfl repack. Grid (32,16), LPT.

__device__ __forceinline__ s16x8 repack_p(
    const unsigned int pk[4][2], int c, int src1, bool selB) {
    int src2 = src1 + 16;
    unsigned int tA0 = pk[2 * c][0], tA1 = pk[2 * c][1];
    unsigned int tB0 = pk[2 * c + 1][0], tB1 = pk[2 * c + 1][1];
    unsigned int a0 = __shfl((int)tA0, src1), a1 = __shfl((int)tA1, src1);
    unsigned int a2 = __shfl((int)tA0, src2), a3 = __shfl((int)tA1, src2);
    unsigned int b0 = __shfl((int)tB0, src1), b1 = __shfl((int)tB1, src1);
    unsigned int b2 = __shfl((int)tB0, src2), b3 = __shfl((int)tB1, src2);
    union { s16x8 v; unsigned int u[4]; } x;
    x.u[0] = selB ? b0 : a0;
    x.u[1] = selB ? b1 : a1;
    x.u[2] = selB ? b2 : a2;
    x.u[3] = selB ? b3 : a3;
    return x.v;
}

__global__ __launch_bounds__(256) void attn(
    const unsigned short* __restrict__ Q, const unsigned short* __restrict__ Kr,
    const unsigned short* __restrict__ Vt, unsigned short* __restrict__ Oa) {
    __shared__ unsigned short KL[2][64 * 64];
    __shared__ unsigned short VL[2][64 * 64];

    int h = blockIdx.x;
    int kvh = h >> 2;
    int qblk = (int)(gridDim.y - 1) - (int)blockIdx.y;  // long blocks first
    int t = threadIdx.x, wave = t >> 6, lane = t & 63, lo = lane & 15, hi = lane >> 4;
    int qw = qblk * 128 + wave * 32;

    int srow = wave * 16 + (lane >> 3);
    int sc = lane & 7;

    s16x8 qf[2][2];
#pragma unroll
    for (int g = 0; g < 2; g++)
#pragma unroll
        for (int hf = 0; hf < 2; hf++)
            qf[g][hf] = *(const s16x8*)(Q + (size_t)(qw + g * 16 + lo) * 2048 +
                                        h * 64 + hf * 32 + hi * 8);

    f32x4 O0[4] = {}, O1[4] = {};
    float m0 = -1e30f, m1 = -1e30f, l0 = 0.f, l1 = 0.f;

    int src1 = lo + ((hi & 1) << 5);
    bool selB = hi >= 2;

    int nt = 2 * qblk + 2;
    int lastw = 2 * qblk + (wave >> 1);
    int qrel0 = (wave & 1) * 32 + lo;
    int swz = (lo & 7);

#define STAGE_KV(buf, kb)                                                          \
    {                                                                              \
        _Pragma("unroll")                                                          \
        for (int j = 0; j < 2; j++) {                                              \
            int r = srow + j * 8;                                                  \
            gll16(Kr + (size_t)((kb) * 64 + r) * 512 + kvh * 64 +                  \
                      ((sc ^ (r & 7)) * 8),                                        \
                  &KL[buf][(wave * 16 + j * 8) * 64]);                             \
            gll16(Vt + (size_t)(kvh * 64 + r) * 2048 + (kb) * 64 +                 \
                      ((sc ^ (r & 7)) * 8),                                        \
                  &VL[buf][(wave * 16 + j * 8) * 64]);                             \
        }                                                                          \
    }

    STAGE_KV(0, 0);
    __syncthreads();

    for (int kb = 0; kb < nt; ++kb) {
        int cur = kb & 1;
        if (kb + 1 < nt) STAGE_KV(cur ^ 1, kb + 1);

        if (kb <= lastw) {
            s16x8 kf[4][2];
#pragma unroll
            for (int tt = 0; tt < 4; tt++)
#pragma unroll
                for (int hf = 0; hf < 2; hf++) {
                    int ch = (hf * 4 + hi) ^ swz;
                    kf[tt][hf] = *(const s16x8*)&KL[cur][(tt * 16 + lo) * 64 + ch * 8];
                }
            s16x8 vf[2][4];
#pragma unroll
            for (int c = 0; c < 2; c++)
#pragma unroll
                for (int dt = 0; dt < 4; dt++) {
                    int ch = (c * 4 + hi) ^ swz;
                    vf[c][dt] = *(const s16x8*)&VL[cur][(dt * 16 + lo) * 64 + ch * 8];
                }

            f32x4 s0[4], s1[4];
            __builtin_amdgcn_s_setprio(1);
#pragma unroll
            for (int tt = 0; tt < 4; tt++) {
                f32x4 z0 = {}, z1 = {};
                z0 = __builtin_amdgcn_mfma_f32_16x16x32_bf16(kf[tt][0], qf[0][0], z0, 0, 0, 0);
                z0 = __builtin_amdgcn_mfma_f32_16x16x32_bf16(kf[tt][1], qf[0][1], z0, 0, 0, 0);
                z1 = __builtin_amdgcn_mfma_f32_16x16x32_bf16(kf[tt][0], qf[1][0], z1, 0, 0, 0);
                z1 = __builtin_amdgcn_mfma_f32_16x16x32_bf16(kf[tt][1], qf[1][1], z1, 0, 0, 0);
                s0[tt] = z0; s1[tt] = z1;
            }
            __builtin_amdgcn_s_setprio(0);

            if (kb == lastw) {
#pragma unroll
                for (int tt = 0; tt < 4; tt++)
#pragma unroll
                    for (int r = 0; r < 4; r++) {
                        int kg = tt * 16 + hi * 4 + r;
                        if (kg > qrel0) s0[tt][r] = -1e30f;
                        if (kg > qrel0 + 16) s1[tt][r] = -1e30f;
                    }
            }

            float mx0 = s0[0][0], mx1 = s1[0][0];
#pragma unroll
            for (int tt = 0; tt < 4; tt++)
#pragma unroll
                for (int r = 0; r < 4; r++) {
                    mx0 = fmaxf(mx0, s0[tt][r]);
                    mx1 = fmaxf(mx1, s1[tt][r]);
                }
            mx0 = fmaxf(mx0, __shfl_xor(mx0, 16));
            mx0 = fmaxf(mx0, __shfl_xor(mx0, 32));
            mx1 = fmaxf(mx1, __shfl_xor(mx1, 16));
            mx1 = fmaxf(mx1, __shfl_xor(mx1, 32));

            if (!__all((mx0 - m0 <= 8.0f) && (mx1 - m1 <= 8.0f))) {
                float mn0 = fmaxf(m0, mx0), mn1 = fmaxf(m1, mx1);
                float al0 = __builtin_amdgcn_exp2f(m0 - mn0);
                float al1 = __builtin_amdgcn_exp2f(m1 - mn1);
                m0 = mn0; m1 = mn1;
                l0 *= al0; l1 *= al1;
                float a0r[4], a1r[4];
#pragma unroll
                for (int r = 0; r < 4; r++) {
                    a0r[r] = __shfl(al0, hi * 4 + r);
                    a1r[r] = __shfl(al1, hi * 4 + r);
                }
#pragma unroll
                for (int dt = 0; dt < 4; dt++)
#pragma unroll
                    for (int r = 0; r < 4; r++) {
                        O0[dt][r] *= a0r[r];
                        O1[dt][r] *= a1r[r];
                    }
            }

            unsigned int pk0[4][2], pk1[4][2];
            float rs0 = 0.f, rs1 = 0.f;
#pragma unroll
            for (int tt = 0; tt < 4; tt++) {
#pragma unroll
                for (int r = 0; r < 4; r++) {
                    float p0 = __builtin_amdgcn_exp2f(s0[tt][r] - m0);
                    float p1 = __builtin_amdgcn_exp2f(s1[tt][r] - m1);
                    s0[tt][r] = p0; s1[tt][r] = p1;
                    rs0 += p0; rs1 += p1;
                }
                unsigned int a, b;
                asm("v_cvt_pk_bf16_f32 %0, %1, %2" : "=v"(a) : "v"(s0[tt][0]), "v"(s0[tt][1]));
                asm("v_cvt_pk_bf16_f32 %0, %1, %2" : "=v"(b) : "v"(s0[tt][2]), "v"(s0[tt][3]));
                pk0[tt][0] = a; pk0[tt][1] = b;
                asm("v_cvt_pk_bf16_f32 %0, %1, %2" : "=v"(a) : "v"(s1[tt][0]), "v"(s1[tt][1]));
                asm("v_cvt_pk_bf16_f32 %0, %1, %2" : "=v"(b) : "v"(s1[tt][2]), "v"(s1[tt][3]));
                pk1[tt][0] = a; pk1[tt][1] = b;
            }
            rs0 += __shfl_xor(rs0, 16);
            rs0 += __shfl_xor(rs0, 32);
            rs1 += __shfl_xor(rs1, 16);
            rs1 += __shfl_xor(rs1, 32);
            l0 += rs0; l1 += rs1;

#pragma unroll
            for (int c = 0; c < 2; c++) {
                s16x8 pa0 = repack_p(pk0, c, src1, selB);
                s16x8 pa1 = repack_p(pk1, c, src1, selB);
                __builtin_amdgcn_s_setprio(1);
#pragma unroll
                for (int dt = 0; dt < 4; dt++) {
                    O0[dt] = __builtin_amdgcn_mfma_f32_16x16x32_bf16(pa0, vf[c][dt], O0[dt], 0, 0, 0);
                    O1[dt] = __builtin_amdgcn_mfma_f32_16x16x32_bf16(pa1, vf[c][dt], O1[dt], 0, 0, 0);
                }
                __builtin_amdgcn_s_setprio(0);
            }
        }
        __syncthreads();
    }

#pragma unroll
    for (int g = 0; g < 2; g++) {
        float lg = g ? l1 : l0;
        f32x4* O = g ? O1 : O0;
        float inv[4];
#pragma unroll
        for (int r = 0; r < 4; r++) inv[r] = 1.0f / __shfl(lg, hi * 4 + r);
        int qrow = qw + g * 16 + hi * 4;
#pragma unroll
        for (int dt = 0; dt < 4; dt++)
#pragma unroll
            for (int r = 0; r < 4; r++)
                Oa[(size_t)(qrow + r) * 2048 + h * 64 + dt * 16 + lo] =
                    f2b(O[dt][r] * inv[r]);
    }
}

extern "C" void kernel_launch(void* const* d_in, const int* in_sizes, int n_in,
                              void* d_out, int out_size, void* d_ws, size_t ws_size,
                              hipStream_t stream) {
    const float* x  = (const float*)d_in[0];
    const float* R  = (const float*)d_in[1];
    // d_in[2] = mask: unused (causal mask applied analytically)
    const float* wq = (const float*)d_in[3];
    const float* wk = (const float*)d_in[4];
    const float* wv = (const float*)d_in[5];
    const float* wo = (const float*)d_in[6];

    float* out0 = (float*)d_out;
    float* outK = out0 + (size_t)2048 * 2048;
    float* outV = outK + (size_t)32 * 2048 * 64;

    char* ws = (char*)d_ws;
    unsigned short* BTall = (unsigned short*)(ws);               // 12 MB [3072][2048]
    unsigned short* woT = (unsigned short*)(ws + 12582912);      // 8 MB
    unsigned short* Qb  = (unsigned short*)(ws + 20971520);      // 8 MB
    unsigned short* Kb  = (unsigned short*)(ws + 29360128);      // 2 MB
    unsigned short* Vb  = (unsigned short*)(ws + 31457280);      // 2 MB
    unsigned short* VtT = (unsigned short*)(ws + 33554432);      // 2 MB [512][2048]
    unsigned short* Ob  = (unsigned short*)(ws + 35651584);      // 8 MB
    float* cosT = (float*)(ws + 44040192);                       // 256 KB
    float* sinT = (float*)(ws + 44302336);                       // 256 KB
    unsigned short* xb  = (unsigned short*)(ws + 44564480);      // 8 MB

    cvt_f32_bf16<<<2048, 256, 0, stream>>>(x, xb);
    transpose_f32_bf16<<<dim3(32, 32), 256, 0, stream>>>(wq, BTall, 2048, 2048);
    transpose_f32_bf16<<<dim3(8, 32), 256, 0, stream>>>(wk, BTall + (size_t)2048 * 2048, 2048, 512);
    transpose_f32_bf16<<<dim3(8, 32), 256, 0, stream>>>(wv, BTall + (size_t)2560 * 2048, 2048, 512);
    transpose_f32_bf16<<<dim3(32, 32), 256, 0, stream>>>(wo, woT, 2048, 2048);
    rope_tables<<<256, 256, 0, stream>>>(R, cosT, sinT);

    gemm_qkv<<<dim3(48, 16), 256, 0, stream>>>(xb, BTall, Qb, Kb, Vb, cosT, sinT, outK);

    v_out<<<512, 256, 0, stream>>>(Vb, outV);
    transpose_bf16<<<dim3(8, 32), 256, 0, stream>>>(Vb, VtT, 2048, 512);

    attn<<<dim3(32, 16), 256, 0, stream>>>(Qb, Kb, VtT, Ob);

    gemm_out<<<dim3(32, 16), 256, 0, stream>>>(Ob, woT, out0, 2048, 2048, 2048);
}

// Round 9
// 183.521 us; speedup vs baseline: 1.1087x; 1.0642x over previous
//
#include <hip/hip_runtime.h>

typedef __attribute__((ext_vector_type(8))) short s16x8;
typedef __attribute__((ext_vector_type(4))) float f32x4;

#define SCALE 0.125f
#define LOG2E 1.4426950408889634f
#define QSC (SCALE * LOG2E)

__device__ inline float b2f(unsigned short u) {
    union { unsigned int i; float f; } x; x.i = ((unsigned int)u) << 16; return x.f;
}
__device__ inline unsigned short f2b(float f) {
    union { float f; unsigned int i; } x; x.f = f;
    unsigned int i = x.i;
    unsigned int r = (i + 0x7FFFu + ((i >> 16) & 1u)) >> 16;
    return (unsigned short)r;
}

// async global->LDS, 16B per lane; lds base must be wave-uniform.
typedef const __attribute__((address_space(1))) unsigned int guint;
typedef __attribute__((address_space(3))) unsigned int luint;
__device__ __forceinline__ void gll16(const void* g, void* l) {
    __builtin_amdgcn_global_load_lds((guint*)g, (luint*)l, 16, 0, 0);
}

// counted-vmcnt barrier: allow newest N loads to stay in flight across it.
#define CBAR(N)                                           \
    do {                                                  \
        asm volatile("s_waitcnt vmcnt(" #N ")" ::: "memory"); \
        __builtin_amdgcn_s_barrier();                     \
        asm volatile("" ::: "memory");                    \
    } while (0)

// ---------------- f32 -> bf16 convert (x) ----------------
__global__ __launch_bounds__(256) void cvt_f32_bf16(
    const float* __restrict__ in, unsigned short* __restrict__ out) {
    int i = (blockIdx.x * 256 + threadIdx.x) * 8;
    f32x4 a = *(const f32x4*)(in + i);
    f32x4 b = *(const f32x4*)(in + i + 4);
    s16x8 o;
    o[0] = (short)f2b(a[0]); o[1] = (short)f2b(a[1]);
    o[2] = (short)f2b(a[2]); o[3] = (short)f2b(a[3]);
    o[4] = (short)f2b(b[0]); o[5] = (short)f2b(b[1]);
    o[6] = (short)f2b(b[2]); o[7] = (short)f2b(b[3]);
    *(s16x8*)(out + i) = o;
}

// ------------- transpose f32 -> bf16: in[R][C] -> out[C][R] -------------
__global__ __launch_bounds__(256) void transpose_f32_bf16(
    const float* __restrict__ in, unsigned short* __restrict__ out,
    int R, int C) {
    __shared__ unsigned short tile[64][72];
    int tc = blockIdx.x * 64, tr = blockIdx.y * 64;
    int t = threadIdx.x;
    int r = t >> 2, cq = (t & 3) * 16;
    const float* src = in + (size_t)(tr + r) * C + tc + cq;
#pragma unroll
    for (int j = 0; j < 16; j += 4) {
        f32x4 v = *(const f32x4*)(src + j);
        tile[r][cq + j]     = f2b(v[0]);
        tile[r][cq + j + 1] = f2b(v[1]);
        tile[r][cq + j + 2] = f2b(v[2]);
        tile[r][cq + j + 3] = f2b(v[3]);
    }
    __syncthreads();
    int oc = t >> 2, rq = (t & 3) * 16;
    s16x8 w0, w1;
#pragma unroll
    for (int j = 0; j < 8; j++) {
        w0[j] = (short)tile[rq + j][oc];
        w1[j] = (short)tile[rq + 8 + j][oc];
    }
    s16x8* dst = (s16x8*)(out + (size_t)(tc + oc) * R + tr + rq);
    dst[0] = w0; dst[1] = w1;
}

// ------------- transpose bf16: in[R][C] -> out[C][R] (for V^T) -------------
__global__ __launch_bounds__(256) void transpose_bf16(
    const unsigned short* __restrict__ in, unsigned short* __restrict__ out,
    int R, int C) {
    __shared__ unsigned short tile[64][72];
    int tc = blockIdx.x * 64, tr = blockIdx.y * 64;
    int t = threadIdx.x;
    int r = t >> 2, cq = (t & 3) * 16;
    const s16x8* src = (const s16x8*)(in + (size_t)(tr + r) * C + tc + cq);
    s16x8 v0 = src[0], v1 = src[1];
    *(s16x8*)&tile[r][cq] = v0;
    *(s16x8*)&tile[r][cq + 8] = v1;
    __syncthreads();
    int oc = t >> 2, rq = (t & 3) * 16;
    s16x8 w0, w1;
#pragma unroll
    for (int j = 0; j < 8; j++) {
        w0[j] = (short)tile[rq + j][oc];
        w1[j] = (short)tile[rq + 8 + j][oc];
    }
    s16x8* dst = (s16x8*)(out + (size_t)(tc + oc) * R + tr + rq);
    dst[0] = w0; dst[1] = w1;
}

// ---------------- RoPE tables from rotation matrix (f32) ----------------
__global__ __launch_bounds__(256) void rope_tables(
    const float* __restrict__ R, float* __restrict__ cosT,
    float* __restrict__ sinT) {
    int idx = blockIdx.x * 256 + threadIdx.x;  // L*32
    int l = idx >> 5, i = idx & 31;
    size_t base = (size_t)l * 4096;
    cosT[idx] = R[base + (size_t)(2 * i) * 64 + 2 * i];
    sinT[idx] = R[base + (size_t)(2 * i + 1) * 64 + 2 * i];
}

// ==== GEMM core: BM=128 x BN=64 x BK=32, triple-buffered LDS, counted vmcnt.
// Per K-step per wave: 2 A + 1 B gll16 -> CBAR(3) keeps newest stage in
// flight across the barrier (no full drain per iteration).

// ---- fused QKV GEMM + RoPE epilogue (+ V/K f32 outputs) ----
__global__ __launch_bounds__(256) void gemm_qkv(
    const unsigned short* __restrict__ A, const unsigned short* __restrict__ BT,
    unsigned short* __restrict__ Qb, unsigned short* __restrict__ Kb,
    unsigned short* __restrict__ Vb, const float* __restrict__ cosT,
    const float* __restrict__ sinT, float* __restrict__ outK,
    float* __restrict__ outV) {
    const int K = 2048;
    __shared__ unsigned short As[3][128 * 32];
    __shared__ unsigned short Bs[3][64 * 32];
    int t = threadIdx.x;
    int w = t >> 6, lane = t & 63, lo = lane & 15, hi = lane >> 4;
    int m0 = blockIdx.y * 128, n0 = blockIdx.x * 64;
    int wr = w >> 1, wc = w & 1;
    int srow = lane >> 2, scol = (lane & 3) * 8;

    const unsigned short* gA = A + (size_t)(m0 + w * 16 + srow) * K + scol;
    const unsigned short* gB = BT + (size_t)(n0 + w * 16 + srow) * K + scol;

#define GSTAGE(buf, kk)                                           \
    {                                                             \
        gll16(gA + (kk), &As[buf][(w * 16) * 32]);                \
        gll16(gA + (size_t)64 * K + (kk), &As[buf][(64 + w * 16) * 32]); \
        gll16(gB + (kk), &Bs[buf][(w * 16) * 32]);                \
    }

    f32x4 acc[4][2] = {};

    GSTAGE(0, 0);
    GSTAGE(1, 32);
    int cur = 0, sb = 2;

    for (int k0 = 0; k0 < K; k0 += 32) {
        CBAR(3);
        if (k0 + 64 < K) GSTAGE(sb, k0 + 64);
        s16x8 af[4], bfr[2];
#pragma unroll
        for (int i = 0; i < 4; i++)
            af[i] = *(const s16x8*)&As[cur][(wr * 64 + i * 16 + lo) * 32 + hi * 8];
#pragma unroll
        for (int j = 0; j < 2; j++)
            bfr[j] = *(const s16x8*)&Bs[cur][(wc * 32 + j * 16 + lo) * 32 + hi * 8];
#pragma unroll
        for (int i = 0; i < 4; i++)
#pragma unroll
            for (int j = 0; j < 2; j++)
                acc[i][j] = __builtin_amdgcn_mfma_f32_16x16x32_bf16(
                    af[i], bfr[j], acc[i][j], 0, 0, 0);
        cur = (cur == 2) ? 0 : cur + 1;
        sb = (sb == 2) ? 0 : sb + 1;
    }

    if (n0 < 2048) {  // ---- Q: rope + QSC ----
#pragma unroll
        for (int i = 0; i < 4; i++)
#pragma unroll
            for (int j = 0; j < 2; j++) {
                int colb = n0 + wc * 32 + j * 16 + lo;
                int d = colb & 63;
                float sgn = (d & 1) ? 1.0f : -1.0f;
                int ip = d >> 1;
#pragma unroll
                for (int r = 0; r < 4; r++) {
                    int row = m0 + wr * 64 + i * 16 + hi * 4 + r;
                    float v = acc[i][j][r];
                    float p = __shfl_xor(v, 1);
                    float c = cosT[row * 32 + ip], s = sinT[row * 32 + ip];
                    float o = (c * v + sgn * s * p) * QSC;
                    Qb[(size_t)row * 2048 + colb] = f2b(o);
                }
            }
    } else if (n0 < 2560) {  // ---- K: rope + repeated f32 out ----
        int cb = n0 - 2048;
#pragma unroll
        for (int i = 0; i < 4; i++)
#pragma unroll
            for (int j = 0; j < 2; j++) {
                int colb = cb + wc * 32 + j * 16 + lo;
                int d = colb & 63;
                int kvh2 = colb >> 6;
                float sgn = (d & 1) ? 1.0f : -1.0f;
                int ip = d >> 1;
#pragma unroll
                for (int r = 0; r < 4; r++) {
                    int row = m0 + wr * 64 + i * 16 + hi * 4 + r;
                    float v = acc[i][j][r];
                    float p = __shfl_xor(v, 1);
                    float c = cosT[row * 32 + ip], s = sinT[row * 32 + ip];
                    float o = c * v + sgn * s * p;
                    Kb[(size_t)row * 512 + colb] = f2b(o);
#pragma unroll
                    for (int rep = 0; rep < 4; rep++) {
                        int h2 = kvh2 * 4 + rep;
                        outK[((size_t)h2 * 2048 + row) * 64 + d] = o;
                    }
                }
            }
    } else {  // ---- V: plain bf16 + repeated f32 out ----
        int cb = n0 - 2560;
#pragma unroll
        for (int i = 0; i < 4; i++)
#pragma unroll
            for (int j = 0; j < 2; j++) {
                int colb = cb + wc * 32 + j * 16 + lo;
                int d = colb & 63;
                int kvh2 = colb >> 6;
#pragma unroll
                for (int r = 0; r < 4; r++) {
                    int row = m0 + wr * 64 + i * 16 + hi * 4 + r;
                    float v = acc[i][j][r];
                    Vb[(size_t)row * 512 + colb] = f2b(v);
#pragma unroll
                    for (int rep = 0; rep < 4; rep++) {
                        int h2 = kvh2 * 4 + rep;
                        outV[((size_t)h2 * 2048 + row) * 64 + d] = v;
                    }
                }
            }
    }
#undef GSTAGE
}

// -------- output GEMM: A[M][K] bf16, BT[N][K] bf16 -> C[M][N] f32 --------
__global__ __launch_bounds__(256) void gemm_out(
    const unsigned short* __restrict__ A, const unsigned short* __restrict__ BT,
    float* __restrict__ C, int M, int N, int K) {
    __shared__ unsigned short As[3][128 * 32];
    __shared__ unsigned short Bs[3][64 * 32];
    int t = threadIdx.x;
    int w = t >> 6, lane = t & 63, lo = lane & 15, hi = lane >> 4;
    int m0 = blockIdx.y * 128, n0 = blockIdx.x * 64;
    int wr = w >> 1, wc = w & 1;
    int srow = lane >> 2, scol = (lane & 3) * 8;

    const unsigned short* gA = A + (size_t)(m0 + w * 16 + srow) * K + scol;
    const unsigned short* gB = BT + (size_t)(n0 + w * 16 + srow) * K + scol;

#define GSTAGE(buf, kk)                                           \
    {                                                             \
        gll16(gA + (kk), &As[buf][(w * 16) * 32]);                \
        gll16(gA + (size_t)64 * K + (kk), &As[buf][(64 + w * 16) * 32]); \
        gll16(gB + (kk), &Bs[buf][(w * 16) * 32]);                \
    }

    f32x4 acc[4][2] = {};

    GSTAGE(0, 0);
    GSTAGE(1, 32);
    int cur = 0, sb = 2;

    for (int k0 = 0; k0 < K; k0 += 32) {
        CBAR(3);
        if (k0 + 64 < K) GSTAGE(sb, k0 + 64);
        s16x8 af[4], bfr[2];
#pragma unroll
        for (int i = 0; i < 4; i++)
            af[i] = *(const s16x8*)&As[cur][(wr * 64 + i * 16 + lo) * 32 + hi * 8];
#pragma unroll
        for (int j = 0; j < 2; j++)
            bfr[j] = *(const s16x8*)&Bs[cur][(wc * 32 + j * 16 + lo) * 32 + hi * 8];
#pragma unroll
        for (int i = 0; i < 4; i++)
#pragma unroll
            for (int j = 0; j < 2; j++)
                acc[i][j] = __builtin_amdgcn_mfma_f32_16x16x32_bf16(
                    af[i], bfr[j], acc[i][j], 0, 0, 0);
        cur = (cur == 2) ? 0 : cur + 1;
        sb = (sb == 2) ? 0 : sb + 1;
    }
#pragma unroll
    for (int i = 0; i < 4; i++)
#pragma unroll
        for (int j = 0; j < 2; j++)
#pragma unroll
            for (int r = 0; r < 4; r++) {
                int row = m0 + wr * 64 + i * 16 + hi * 4 + r;
                int col = n0 + wc * 32 + j * 16 + lo;
                C[(size_t)row * N + col] = acc[i][j][r];
            }
#undef GSTAGE
}

// ====================== flash attention (causal) ======================
// Round-6 structure + T3/T4: triple-buffered K/V^T LDS tiles, raw barrier
// with counted vmcnt(4) (one stage = 4 gll16/wave stays in flight across
// the barrier). 4 waves/block, 128 q-rows; grid (32 h, 16 qblk), LPT.

__device__ __forceinline__ s16x8 repack_p(
    const unsigned int pk[4][2], int c, int src1, bool selB) {
    int src2 = src1 + 16;
    unsigned int tA0 = pk[2 * c][0], tA1 = pk[2 * c][1];
    unsigned int tB0 = pk[2 * c + 1][0], tB1 = pk[2 * c + 1][1];
    unsigned int a0 = __shfl((int)tA0, src1), a1 = __shfl((int)tA1, src1);
    unsigned int a2 = __shfl((int)tA0, src2), a3 = __shfl((int)tA1, src2);
    unsigned int b0 = __shfl((int)tB0, src1), b1 = __shfl((int)tB1, src1);
    unsigned int b2 = __shfl((int)tB0, src2), b3 = __shfl((int)tB1, src2);
    union { s16x8 v; unsigned int u[4]; } x;
    x.u[0] = selB ? b0 : a0;
    x.u[1] = selB ? b1 : a1;
    x.u[2] = selB ? b2 : a2;
    x.u[3] = selB ? b3 : a3;
    return x.v;
}

__global__ __launch_bounds__(256) void attn(
    const unsigned short* __restrict__ Q, const unsigned short* __restrict__ Kr,
    const unsigned short* __restrict__ Vt, unsigned short* __restrict__ Oa) {
    __shared__ unsigned short KL[3][64 * 64];
    __shared__ unsigned short VL[3][64 * 64];

    int h = blockIdx.x;
    int kvh = h >> 2;
    int qblk = (int)(gridDim.y - 1) - (int)blockIdx.y;  // long blocks first
    int t = threadIdx.x, wave = t >> 6, lane = t & 63, lo = lane & 15, hi = lane >> 4;
    int qw = qblk * 128 + wave * 32;

    int srow = wave * 16 + (lane >> 3);
    int sc = lane & 7;

    s16x8 qf[2][2];
#pragma unroll
    for (int g = 0; g < 2; g++)
#pragma unroll
        for (int hf = 0; hf < 2; hf++)
            qf[g][hf] = *(const s16x8*)(Q + (size_t)(qw + g * 16 + lo) * 2048 +
                                        h * 64 + hf * 32 + hi * 8);

    f32x4 O0[4] = {}, O1[4] = {};
    float m0 = -1e30f, m1 = -1e30f, l0 = 0.f, l1 = 0.f;

    int src1 = lo + ((hi & 1) << 5);
    bool selB = hi >= 2;

    int nt = 2 * qblk + 2;
    int lastw = 2 * qblk + (wave >> 1);
    int qrel0 = (wave & 1) * 32 + lo;
    int swz = (lo & 7);

#define STAGE_KV(buf, kb)                                                          \
    {                                                                              \
        _Pragma("unroll")                                                          \
        for (int j = 0; j < 2; j++) {                                              \
            int r = srow + j * 8;                                                  \
            gll16(Kr + (size_t)((kb) * 64 + r) * 512 + kvh * 64 +                  \
                      ((sc ^ (r & 7)) * 8),                                        \
                  &KL[buf][(wave * 16 + j * 8) * 64]);                             \
            gll16(Vt + (size_t)(kvh * 64 + r) * 2048 + (kb) * 64 +                 \
                      ((sc ^ (r & 7)) * 8),                                        \
                  &VL[buf][(wave * 16 + j * 8) * 64]);                             \
        }                                                                          \
    }

    STAGE_KV(0, 0);
    STAGE_KV(1, 1);
    int cur = 0, sb = 2;

    for (int kb = 0; kb < nt; ++kb) {
        CBAR(4);
        if (kb + 2 < nt) STAGE_KV(sb, kb + 2);

        if (kb <= lastw) {
            s16x8 kf[4][2];
#pragma unroll
            for (int tt = 0; tt < 4; tt++)
#pragma unroll
                for (int hf = 0; hf < 2; hf++) {
                    int ch = (hf * 4 + hi) ^ swz;
                    kf[tt][hf] = *(const s16x8*)&KL[cur][(tt * 16 + lo) * 64 + ch * 8];
                }
            s16x8 vf[2][4];
#pragma unroll
            for (int c = 0; c < 2; c++)
#pragma unroll
                for (int dt = 0; dt < 4; dt++) {
                    int ch = (c * 4 + hi) ^ swz;
                    vf[c][dt] = *(const s16x8*)&VL[cur][(dt * 16 + lo) * 64 + ch * 8];
                }

            f32x4 s0[4], s1[4];
            __builtin_amdgcn_s_setprio(1);
#pragma unroll
            for (int tt = 0; tt < 4; tt++) {
                f32x4 z0 = {}, z1 = {};
                z0 = __builtin_amdgcn_mfma_f32_16x16x32_bf16(kf[tt][0], qf[0][0], z0, 0, 0, 0);
                z0 = __builtin_amdgcn_mfma_f32_16x16x32_bf16(kf[tt][1], qf[0][1], z0, 0, 0, 0);
                z1 = __builtin_amdgcn_mfma_f32_16x16x32_bf16(kf[tt][0], qf[1][0], z1, 0, 0, 0);
                z1 = __builtin_amdgcn_mfma_f32_16x16x32_bf16(kf[tt][1], qf[1][1], z1, 0, 0, 0);
                s0[tt] = z0; s1[tt] = z1;
            }
            __builtin_amdgcn_s_setprio(0);

            if (kb == lastw) {
#pragma unroll
                for (int tt = 0; tt < 4; tt++)
#pragma unroll
                    for (int r = 0; r < 4; r++) {
                        int kg = tt * 16 + hi * 4 + r;
                        if (kg > qrel0) s0[tt][r] = -1e30f;
                        if (kg > qrel0 + 16) s1[tt][r] = -1e30f;
                    }
            }

            float mx0 = s0[0][0], mx1 = s1[0][0];
#pragma unroll
            for (int tt = 0; tt < 4; tt++)
#pragma unroll
                for (int r = 0; r < 4; r++) {
                    mx0 = fmaxf(mx0, s0[tt][r]);
                    mx1 = fmaxf(mx1, s1[tt][r]);
                }
            mx0 = fmaxf(mx0, __shfl_xor(mx0, 16));
            mx0 = fmaxf(mx0, __shfl_xor(mx0, 32));
            mx1 = fmaxf(mx1, __shfl_xor(mx1, 16));
            mx1 = fmaxf(mx1, __shfl_xor(mx1, 32));

            if (!__all((mx0 - m0 <= 8.0f) && (mx1 - m1 <= 8.0f))) {
                float mn0 = fmaxf(m0, mx0), mn1 = fmaxf(m1, mx1);
                float al0 = __builtin_amdgcn_exp2f(m0 - mn0);
                float al1 = __builtin_amdgcn_exp2f(m1 - mn1);
                m0 = mn0; m1 = mn1;
                l0 *= al0; l1 *= al1;
                float a0r[4], a1r[4];
#pragma unroll
                for (int r = 0; r < 4; r++) {
                    a0r[r] = __shfl(al0, hi * 4 + r);
                    a1r[r] = __shfl(al1, hi * 4 + r);
                }
#pragma unroll
                for (int dt = 0; dt < 4; dt++)
#pragma unroll
                    for (int r = 0; r < 4; r++) {
                        O0[dt][r] *= a0r[r];
                        O1[dt][r] *= a1r[r];
                    }
            }

            unsigned int pk0[4][2], pk1[4][2];
            float rs0 = 0.f, rs1 = 0.f;
#pragma unroll
            for (int tt = 0; tt < 4; tt++) {
#pragma unroll
                for (int r = 0; r < 4; r++) {
                    float p0 = __builtin_amdgcn_exp2f(s0[tt][r] - m0);
                    float p1 = __builtin_amdgcn_exp2f(s1[tt][r] - m1);
                    s0[tt][r] = p0; s1[tt][r] = p1;
                    rs0 += p0; rs1 += p1;
                }
                unsigned int a, b;
                asm("v_cvt_pk_bf16_f32 %0, %1, %2" : "=v"(a) : "v"(s0[tt][0]), "v"(s0[tt][1]));
                asm("v_cvt_pk_bf16_f32 %0, %1, %2" : "=v"(b) : "v"(s0[tt][2]), "v"(s0[tt][3]));
                pk0[tt][0] = a; pk0[tt][1] = b;
                asm("v_cvt_pk_bf16_f32 %0, %1, %2" : "=v"(a) : "v"(s1[tt][0]), "v"(s1[tt][1]));
                asm("v_cvt_pk_bf16_f32 %0, %1, %2" : "=v"(b) : "v"(s1[tt][2]), "v"(s1[tt][3]));
                pk1[tt][0] = a; pk1[tt][1] = b;
            }
            rs0 += __shfl_xor(rs0, 16);
            rs0 += __shfl_xor(rs0, 32);
            rs1 += __shfl_xor(rs1, 16);
            rs1 += __shfl_xor(rs1, 32);
            l0 += rs0; l1 += rs1;

#pragma unroll
            for (int c = 0; c < 2; c++) {
                s16x8 pa0 = repack_p(pk0, c, src1, selB);
                s16x8 pa1 = repack_p(pk1, c, src1, selB);
                __builtin_amdgcn_s_setprio(1);
#pragma unroll
                for (int dt = 0; dt < 4; dt++) {
                    O0[dt] = __builtin_amdgcn_mfma_f32_16x16x32_bf16(pa0, vf[c][dt], O0[dt], 0, 0, 0);
                    O1[dt] = __builtin_amdgcn_mfma_f32_16x16x32_bf16(pa1, vf[c][dt], O1[dt], 0, 0, 0);
                }
                __builtin_amdgcn_s_setprio(0);
            }
        }

        cur = (cur == 2) ? 0 : cur + 1;
        sb = (sb == 2) ? 0 : sb + 1;
    }

#pragma unroll
    for (int g = 0; g < 2; g++) {
        float lg = g ? l1 : l0;
        f32x4* O = g ? O1 : O0;
        float inv[4];
#pragma unroll
        for (int r = 0; r < 4; r++) inv[r] = 1.0f / __shfl(lg, hi * 4 + r);
        int qrow = qw + g * 16 + hi * 4;
#pragma unroll
        for (int dt = 0; dt < 4; dt++)
#pragma unroll
            for (int r = 0; r < 4; r++)
                Oa[(size_t)(qrow + r) * 2048 + h * 64 + dt * 16 + lo] =
                    f2b(O[dt][r] * inv[r]);
    }
}

extern "C" void kernel_launch(void* const* d_in, const int* in_sizes, int n_in,
                              void* d_out, int out_size, void* d_ws, size_t ws_size,
                              hipStream_t stream) {
    const float* x  = (const float*)d_in[0];
    const float* R  = (const float*)d_in[1];
    // d_in[2] = mask: unused (causal mask applied analytically)
    const float* wq = (const float*)d_in[3];
    const float* wk = (const float*)d_in[4];
    const float* wv = (const float*)d_in[5];
    const float* wo = (const float*)d_in[6];

    float* out0 = (float*)d_out;
    float* outK = out0 + (size_t)2048 * 2048;
    float* outV = outK + (size_t)32 * 2048 * 64;

    char* ws = (char*)d_ws;
    unsigned short* BTall = (unsigned short*)(ws);               // 12 MB [3072][2048]
    unsigned short* woT = (unsigned short*)(ws + 12582912);      // 8 MB
    unsigned short* Qb  = (unsigned short*)(ws + 20971520);      // 8 MB
    unsigned short* Kb  = (unsigned short*)(ws + 29360128);      // 2 MB
    unsigned short* Vb  = (unsigned short*)(ws + 31457280);      // 2 MB
    unsigned short* VtT = (unsigned short*)(ws + 33554432);      // 2 MB [512][2048]
    unsigned short* Ob  = (unsigned short*)(ws + 35651584);      // 8 MB
    float* cosT = (float*)(ws + 44040192);                       // 256 KB
    float* sinT = (float*)(ws + 44302336);                       // 256 KB
    unsigned short* xb  = (unsigned short*)(ws + 44564480);      // 8 MB

    cvt_f32_bf16<<<2048, 256, 0, stream>>>(x, xb);
    transpose_f32_bf16<<<dim3(32, 32), 256, 0, stream>>>(wq, BTall, 2048, 2048);
    transpose_f32_bf16<<<dim3(8, 32), 256, 0, stream>>>(wk, BTall + (size_t)2048 * 2048, 2048, 512);
    transpose_f32_bf16<<<dim3(8, 32), 256, 0, stream>>>(wv, BTall + (size_t)2560 * 2048, 2048, 512);
    transpose_f32_bf16<<<dim3(32, 32), 256, 0, stream>>>(wo, woT, 2048, 2048);
    rope_tables<<<256, 256, 0, stream>>>(R, cosT, sinT);

    gemm_qkv<<<dim3(48, 16), 256, 0, stream>>>(xb, BTall, Qb, Kb, Vb, cosT, sinT, outK, outV);

    transpose_bf16<<<dim3(8, 32), 256, 0, stream>>>(Vb, VtT, 2048, 512);

    attn<<<dim3(32, 16), 256, 0, stream>>>(Qb, Kb, VtT, Ob);

    gemm_out<<<dim3(32, 16), 256, 0, stream>>>(Ob, woT, out0, 2048, 2048, 2048);
}

// Round 10
// 170.738 us; speedup vs baseline: 1.1917x; 1.0749x over previous
//
#include <hip/hip_runtime.h>

typedef __attribute__((ext_vector_type(8))) short s16x8;
typedef __attribute__((ext_vector_type(4))) float f32x4;

#define SCALE 0.125f
#define LOG2E 1.4426950408889634f
#define QSC (SCALE * LOG2E)

__device__ inline float b2f(unsigned short u) {
    union { unsigned int i; float f; } x; x.i = ((unsigned int)u) << 16; return x.f;
}
__device__ inline unsigned short f2b(float f) {
    union { float f; unsigned int i; } x; x.f = f;
    unsigned int i = x.i;
    unsigned int r = (i + 0x7FFFu + ((i >> 16) & 1u)) >> 16;
    return (unsigned short)r;
}

// async global->LDS, 16B per lane; lds base must be wave-uniform.
typedef const __attribute__((address_space(1))) unsigned int guint;
typedef __attribute__((address_space(3))) unsigned int luint;
__device__ __forceinline__ void gll16(const void* g, void* l) {
    __builtin_amdgcn_global_load_lds((guint*)g, (luint*)l, 16, 0, 0);
}

// counted-vmcnt barrier: allow newest N loads to stay in flight across it.
#define CBAR(N)                                           \
    do {                                                  \
        asm volatile("s_waitcnt vmcnt(" #N ")" ::: "memory"); \
        __builtin_amdgcn_s_barrier();                     \
        asm volatile("" ::: "memory");                    \
    } while (0)

// ---------------- f32 -> bf16 convert (x) ----------------
__global__ __launch_bounds__(256) void cvt_f32_bf16(
    const float* __restrict__ in, unsigned short* __restrict__ out) {
    int i = (blockIdx.x * 256 + threadIdx.x) * 8;
    f32x4 a = *(const f32x4*)(in + i);
    f32x4 b = *(const f32x4*)(in + i + 4);
    s16x8 o;
    o[0] = (short)f2b(a[0]); o[1] = (short)f2b(a[1]);
    o[2] = (short)f2b(a[2]); o[3] = (short)f2b(a[3]);
    o[4] = (short)f2b(b[0]); o[5] = (short)f2b(b[1]);
    o[6] = (short)f2b(b[2]); o[7] = (short)f2b(b[3]);
    *(s16x8*)(out + i) = o;
}

// ------------- transpose f32 -> bf16: in[R][C] -> out[C][R] -------------
__global__ __launch_bounds__(256) void transpose_f32_bf16(
    const float* __restrict__ in, unsigned short* __restrict__ out,
    int R, int C) {
    __shared__ unsigned short tile[64][72];
    int tc = blockIdx.x * 64, tr = blockIdx.y * 64;
    int t = threadIdx.x;
    int r = t >> 2, cq = (t & 3) * 16;
    const float* src = in + (size_t)(tr + r) * C + tc + cq;
#pragma unroll
    for (int j = 0; j < 16; j += 4) {
        f32x4 v = *(const f32x4*)(src + j);
        tile[r][cq + j]     = f2b(v[0]);
        tile[r][cq + j + 1] = f2b(v[1]);
        tile[r][cq + j + 2] = f2b(v[2]);
        tile[r][cq + j + 3] = f2b(v[3]);
    }
    __syncthreads();
    int oc = t >> 2, rq = (t & 3) * 16;
    s16x8 w0, w1;
#pragma unroll
    for (int j = 0; j < 8; j++) {
        w0[j] = (short)tile[rq + j][oc];
        w1[j] = (short)tile[rq + 8 + j][oc];
    }
    s16x8* dst = (s16x8*)(out + (size_t)(tc + oc) * R + tr + rq);
    dst[0] = w0; dst[1] = w1;
}

// ------------- transpose bf16: in[R][C] -> out[C][R] (for V^T) -------------
__global__ __launch_bounds__(256) void transpose_bf16(
    const unsigned short* __restrict__ in, unsigned short* __restrict__ out,
    int R, int C) {
    __shared__ unsigned short tile[64][72];
    int tc = blockIdx.x * 64, tr = blockIdx.y * 64;
    int t = threadIdx.x;
    int r = t >> 2, cq = (t & 3) * 16;
    const s16x8* src = (const s16x8*)(in + (size_t)(tr + r) * C + tc + cq);
    s16x8 v0 = src[0], v1 = src[1];
    *(s16x8*)&tile[r][cq] = v0;
    *(s16x8*)&tile[r][cq + 8] = v1;
    __syncthreads();
    int oc = t >> 2, rq = (t & 3) * 16;
    s16x8 w0, w1;
#pragma unroll
    for (int j = 0; j < 8; j++) {
        w0[j] = (short)tile[rq + j][oc];
        w1[j] = (short)tile[rq + 8 + j][oc];
    }
    s16x8* dst = (s16x8*)(out + (size_t)(tc + oc) * R + tr + rq);
    dst[0] = w0; dst[1] = w1;
}

// ---------------- RoPE tables from rotation matrix (f32) ----------------
__global__ __launch_bounds__(256) void rope_tables(
    const float* __restrict__ R, float* __restrict__ cosT,
    float* __restrict__ sinT) {
    int idx = blockIdx.x * 256 + threadIdx.x;  // L*32
    int l = idx >> 5, i = idx & 31;
    size_t base = (size_t)l * 4096;
    cosT[idx] = R[base + (size_t)(2 * i) * 64 + 2 * i];
    sinT[idx] = R[base + (size_t)(2 * i + 1) * 64 + 2 * i];
}

// ==== GEMM core: BM=128 x BN=64 x BK=32, triple-buffered LDS, counted vmcnt.

// ---- fused QKV GEMM + RoPE epilogue (+ V/K f32 outputs) ----
__global__ __launch_bounds__(256) void gemm_qkv(
    const unsigned short* __restrict__ A, const unsigned short* __restrict__ BT,
    unsigned short* __restrict__ Qb, unsigned short* __restrict__ Kb,
    unsigned short* __restrict__ Vb, const float* __restrict__ cosT,
    const float* __restrict__ sinT, float* __restrict__ outK,
    float* __restrict__ outV) {
    const int K = 2048;
    __shared__ unsigned short As[3][128 * 32];
    __shared__ unsigned short Bs[3][64 * 32];
    int t = threadIdx.x;
    int w = t >> 6, lane = t & 63, lo = lane & 15, hi = lane >> 4;
    int m0 = blockIdx.y * 128, n0 = blockIdx.x * 64;
    int wr = w >> 1, wc = w & 1;
    int srow = lane >> 2, scol = (lane & 3) * 8;

    const unsigned short* gA = A + (size_t)(m0 + w * 16 + srow) * K + scol;
    const unsigned short* gB = BT + (size_t)(n0 + w * 16 + srow) * K + scol;

#define GSTAGE(buf, kk)                                           \
    {                                                             \
        gll16(gA + (kk), &As[buf][(w * 16) * 32]);                \
        gll16(gA + (size_t)64 * K + (kk), &As[buf][(64 + w * 16) * 32]); \
        gll16(gB + (kk), &Bs[buf][(w * 16) * 32]);                \
    }

    f32x4 acc[4][2] = {};

    GSTAGE(0, 0);
    GSTAGE(1, 32);
    int cur = 0, sb = 2;

    for (int k0 = 0; k0 < K; k0 += 32) {
        CBAR(3);
        if (k0 + 64 < K) GSTAGE(sb, k0 + 64);
        s16x8 af[4], bfr[2];
#pragma unroll
        for (int i = 0; i < 4; i++)
            af[i] = *(const s16x8*)&As[cur][(wr * 64 + i * 16 + lo) * 32 + hi * 8];
#pragma unroll
        for (int j = 0; j < 2; j++)
            bfr[j] = *(const s16x8*)&Bs[cur][(wc * 32 + j * 16 + lo) * 32 + hi * 8];
#pragma unroll
        for (int i = 0; i < 4; i++)
#pragma unroll
            for (int j = 0; j < 2; j++)
                acc[i][j] = __builtin_amdgcn_mfma_f32_16x16x32_bf16(
                    af[i], bfr[j], acc[i][j], 0, 0, 0);
        cur = (cur == 2) ? 0 : cur + 1;
        sb = (sb == 2) ? 0 : sb + 1;
    }

    if (n0 < 2048) {  // ---- Q: rope + QSC ----
#pragma unroll
        for (int i = 0; i < 4; i++)
#pragma unroll
            for (int j = 0; j < 2; j++) {
                int colb = n0 + wc * 32 + j * 16 + lo;
                int d = colb & 63;
                float sgn = (d & 1) ? 1.0f : -1.0f;
                int ip = d >> 1;
#pragma unroll
                for (int r = 0; r < 4; r++) {
                    int row = m0 + wr * 64 + i * 16 + hi * 4 + r;
                    float v = acc[i][j][r];
                    float p = __shfl_xor(v, 1);
                    float c = cosT[row * 32 + ip], s = sinT[row * 32 + ip];
                    float o = (c * v + sgn * s * p) * QSC;
                    Qb[(size_t)row * 2048 + colb] = f2b(o);
                }
            }
    } else if (n0 < 2560) {  // ---- K: rope + repeated f32 out ----
        int cb = n0 - 2048;
#pragma unroll
        for (int i = 0; i < 4; i++)
#pragma unroll
            for (int j = 0; j < 2; j++) {
                int colb = cb + wc * 32 + j * 16 + lo;
                int d = colb & 63;
                int kvh2 = colb >> 6;
                float sgn = (d & 1) ? 1.0f : -1.0f;
                int ip = d >> 1;
#pragma unroll
                for (int r = 0; r < 4; r++) {
                    int row = m0 + wr * 64 + i * 16 + hi * 4 + r;
                    float v = acc[i][j][r];
                    float p = __shfl_xor(v, 1);
                    float c = cosT[row * 32 + ip], s = sinT[row * 32 + ip];
                    float o = c * v + sgn * s * p;
                    Kb[(size_t)row * 512 + colb] = f2b(o);
#pragma unroll
                    for (int rep = 0; rep < 4; rep++) {
                        int h2 = kvh2 * 4 + rep;
                        outK[((size_t)h2 * 2048 + row) * 64 + d] = o;
                    }
                }
            }
    } else {  // ---- V: plain bf16 + repeated f32 out ----
        int cb = n0 - 2560;
#pragma unroll
        for (int i = 0; i < 4; i++)
#pragma unroll
            for (int j = 0; j < 2; j++) {
                int colb = cb + wc * 32 + j * 16 + lo;
                int d = colb & 63;
                int kvh2 = colb >> 6;
#pragma unroll
                for (int r = 0; r < 4; r++) {
                    int row = m0 + wr * 64 + i * 16 + hi * 4 + r;
                    float v = acc[i][j][r];
                    Vb[(size_t)row * 512 + colb] = f2b(v);
#pragma unroll
                    for (int rep = 0; rep < 4; rep++) {
                        int h2 = kvh2 * 4 + rep;
                        outV[((size_t)h2 * 2048 + row) * 64 + d] = v;
                    }
                }
            }
    }
#undef GSTAGE
}

// -------- output GEMM: A[M][K] bf16, BT[N][K] bf16 -> C[M][N] f32 --------
__global__ __launch_bounds__(256) void gemm_out(
    const unsigned short* __restrict__ A, const unsigned short* __restrict__ BT,
    float* __restrict__ C, int M, int N, int K) {
    __shared__ unsigned short As[3][128 * 32];
    __shared__ unsigned short Bs[3][64 * 32];
    int t = threadIdx.x;
    int w = t >> 6, lane = t & 63, lo = lane & 15, hi = lane >> 4;
    int m0 = blockIdx.y * 128, n0 = blockIdx.x * 64;
    int wr = w >> 1, wc = w & 1;
    int srow = lane >> 2, scol = (lane & 3) * 8;

    const unsigned short* gA = A + (size_t)(m0 + w * 16 + srow) * K + scol;
    const unsigned short* gB = BT + (size_t)(n0 + w * 16 + srow) * K + scol;

#define GSTAGE(buf, kk)                                           \
    {                                                             \
        gll16(gA + (kk), &As[buf][(w * 16) * 32]);                \
        gll16(gA + (size_t)64 * K + (kk), &As[buf][(64 + w * 16) * 32]); \
        gll16(gB + (kk), &Bs[buf][(w * 16) * 32]);                \
    }

    f32x4 acc[4][2] = {};

    GSTAGE(0, 0);
    GSTAGE(1, 32);
    int cur = 0, sb = 2;

    for (int k0 = 0; k0 < K; k0 += 32) {
        CBAR(3);
        if (k0 + 64 < K) GSTAGE(sb, k0 + 64);
        s16x8 af[4], bfr[2];
#pragma unroll
        for (int i = 0; i < 4; i++)
            af[i] = *(const s16x8*)&As[cur][(wr * 64 + i * 16 + lo) * 32 + hi * 8];
#pragma unroll
        for (int j = 0; j < 2; j++)
            bfr[j] = *(const s16x8*)&Bs[cur][(wc * 32 + j * 16 + lo) * 32 + hi * 8];
#pragma unroll
        for (int i = 0; i < 4; i++)
#pragma unroll
            for (int j = 0; j < 2; j++)
                acc[i][j] = __builtin_amdgcn_mfma_f32_16x16x32_bf16(
                    af[i], bfr[j], acc[i][j], 0, 0, 0);
        cur = (cur == 2) ? 0 : cur + 1;
        sb = (sb == 2) ? 0 : sb + 1;
    }
#pragma unroll
    for (int i = 0; i < 4; i++)
#pragma unroll
        for (int j = 0; j < 2; j++)
#pragma unroll
            for (int r = 0; r < 4; r++) {
                int row = m0 + wr * 64 + i * 16 + hi * 4 + r;
                int col = n0 + wc * 32 + j * 16 + lo;
                C[(size_t)row * N + col] = acc[i][j][r];
            }
#undef GSTAGE
}

// ====================== flash attention (causal) ======================
// 512 EQUAL blocks: grid (32 h, 16 p); each 4-wave block serially handles
// strip pair (p, 31-p) of 64 q-rows (16 rows/wave) -> exactly 33 k-tiles
// per block, all blocks identical, 2 blocks/CU resident, no tail.
// Triple-buffered K/V^T LDS, gll16-staged (XOR-preswizzled source),
// counted vmcnt(4) across raw barriers. Swapped QK^T; in-reg softmax with
// defer-max; cvt_pk + shfl repack into PV A-fragment.

__device__ __forceinline__ s16x8 repack_p(
    const unsigned int pk[4][2], int c, int src1, bool selB) {
    int src2 = src1 + 16;
    unsigned int tA0 = pk[2 * c][0], tA1 = pk[2 * c][1];
    unsigned int tB0 = pk[2 * c + 1][0], tB1 = pk[2 * c + 1][1];
    unsigned int a0 = __shfl((int)tA0, src1), a1 = __shfl((int)tA1, src1);
    unsigned int a2 = __shfl((int)tA0, src2), a3 = __shfl((int)tA1, src2);
    unsigned int b0 = __shfl((int)tB0, src1), b1 = __shfl((int)tB1, src1);
    unsigned int b2 = __shfl((int)tB0, src2), b3 = __shfl((int)tB1, src2);
    union { s16x8 v; unsigned int u[4]; } x;
    x.u[0] = selB ? b0 : a0;
    x.u[1] = selB ? b1 : a1;
    x.u[2] = selB ? b2 : a2;
    x.u[3] = selB ? b3 : a3;
    return x.v;
}

__global__ __launch_bounds__(256) void attn(
    const unsigned short* __restrict__ Q, const unsigned short* __restrict__ Kr,
    const unsigned short* __restrict__ Vt, unsigned short* __restrict__ Oa) {
    __shared__ unsigned short KL[3][64 * 64];
    __shared__ unsigned short VL[3][64 * 64];

    int h = blockIdx.x;
    int kvh = h >> 2;
    int p = blockIdx.y;  // 0..15 -> strips (p, 31-p)
    int t = threadIdx.x, wave = t >> 6, lane = t & 63, lo = lane & 15, hi = lane >> 4;

    int srow = wave * 16 + (lane >> 3);
    int sc = lane & 7;
    int src1 = lo + ((hi & 1) << 5);
    bool selB = hi >= 2;
    int swz = lo & 7;
    int qrel = wave * 16 + lo;  // within-diag-tile q offset

#define STAGE_KV(buf, kb)                                                          \
    {                                                                              \
        _Pragma("unroll")                                                          \
        for (int j = 0; j < 2; j++) {                                              \
            int r = srow + j * 8;                                                  \
            gll16(Kr + (size_t)((kb) * 64 + r) * 512 + kvh * 64 +                  \
                      ((sc ^ (r & 7)) * 8),                                        \
                  &KL[buf][(wave * 16 + j * 8) * 64]);                             \
            gll16(Vt + (size_t)(kvh * 64 + r) * 2048 + (kb) * 64 +                 \
                      ((sc ^ (r & 7)) * 8),                                        \
                  &VL[buf][(wave * 16 + j * 8) * 64]);                             \
        }                                                                          \
    }

#pragma unroll 1
    for (int part = 0; part < 2; ++part) {
        int s = part ? (31 - p) : p;  // 64-row strip index; tiles 0..s
        int qw = s * 64 + wave * 16;

        s16x8 qf[2];
#pragma unroll
        for (int hf = 0; hf < 2; hf++)
            qf[hf] = *(const s16x8*)(Q + (size_t)(qw + lo) * 2048 +
                                     h * 64 + hf * 32 + hi * 8);

        f32x4 O[4] = {};
        float m = -1e30f, l = 0.f;

        STAGE_KV(0, 0);
        STAGE_KV(1, (s > 0 ? 1 : 0));
        int cur = 0, sb = 2;

        for (int kb = 0; kb <= s; ++kb) {
            CBAR(4);
            int nx = (kb + 2 > s) ? s : kb + 2;
            STAGE_KV(sb, nx);

            s16x8 kf[4][2];
#pragma unroll
            for (int tt = 0; tt < 4; tt++)
#pragma unroll
                for (int hf = 0; hf < 2; hf++) {
                    int ch = (hf * 4 + hi) ^ swz;
                    kf[tt][hf] = *(const s16x8*)&KL[cur][(tt * 16 + lo) * 64 + ch * 8];
                }
            s16x8 vf[2][4];
#pragma unroll
            for (int c = 0; c < 2; c++)
#pragma unroll
                for (int dt = 0; dt < 4; dt++) {
                    int ch = (c * 4 + hi) ^ swz;
                    vf[c][dt] = *(const s16x8*)&VL[cur][(dt * 16 + lo) * 64 + ch * 8];
                }

            f32x4 s0[4];
            __builtin_amdgcn_s_setprio(1);
#pragma unroll
            for (int tt = 0; tt < 4; tt++) {
                f32x4 z0 = {};
                z0 = __builtin_amdgcn_mfma_f32_16x16x32_bf16(kf[tt][0], qf[0], z0, 0, 0, 0);
                z0 = __builtin_amdgcn_mfma_f32_16x16x32_bf16(kf[tt][1], qf[1], z0, 0, 0, 0);
                s0[tt] = z0;
            }
            __builtin_amdgcn_s_setprio(0);

            if (kb == s) {  // diagonal tile: causal mask
#pragma unroll
                for (int tt = 0; tt < 4; tt++)
#pragma unroll
                    for (int r = 0; r < 4; r++) {
                        int kg = tt * 16 + hi * 4 + r;
                        if (kg > qrel) s0[tt][r] = -1e30f;
                    }
            }

            // ---- online softmax with defer-max (THR = 8, log2 units) ----
            float mx = s0[0][0];
#pragma unroll
            for (int tt = 0; tt < 4; tt++)
#pragma unroll
                for (int r = 0; r < 4; r++) mx = fmaxf(mx, s0[tt][r]);
            mx = fmaxf(mx, __shfl_xor(mx, 16));
            mx = fmaxf(mx, __shfl_xor(mx, 32));

            if (!__all(mx - m <= 8.0f)) {
                float mn = fmaxf(m, mx);
                float al = __builtin_amdgcn_exp2f(m - mn);
                m = mn;
                l *= al;
                float alr[4];
#pragma unroll
                for (int r = 0; r < 4; r++) alr[r] = __shfl(al, hi * 4 + r);
#pragma unroll
                for (int dt = 0; dt < 4; dt++)
#pragma unroll
                    for (int r = 0; r < 4; r++) O[dt][r] *= alr[r];
            }

            unsigned int pk[4][2];
            float rs = 0.f;
#pragma unroll
            for (int tt = 0; tt < 4; tt++) {
#pragma unroll
                for (int r = 0; r < 4; r++) {
                    float pv = __builtin_amdgcn_exp2f(s0[tt][r] - m);
                    s0[tt][r] = pv;
                    rs += pv;
                }
                unsigned int a, b;
                asm("v_cvt_pk_bf16_f32 %0, %1, %2" : "=v"(a) : "v"(s0[tt][0]), "v"(s0[tt][1]));
                asm("v_cvt_pk_bf16_f32 %0, %1, %2" : "=v"(b) : "v"(s0[tt][2]), "v"(s0[tt][3]));
                pk[tt][0] = a; pk[tt][1] = b;
            }
            rs += __shfl_xor(rs, 16);
            rs += __shfl_xor(rs, 32);
            l += rs;

#pragma unroll
            for (int c = 0; c < 2; c++) {
                s16x8 pa = repack_p(pk, c, src1, selB);
                __builtin_amdgcn_s_setprio(1);
#pragma unroll
                for (int dt = 0; dt < 4; dt++)
                    O[dt] = __builtin_amdgcn_mfma_f32_16x16x32_bf16(pa, vf[c][dt], O[dt], 0, 0, 0);
                __builtin_amdgcn_s_setprio(0);
            }

            cur = (cur == 2) ? 0 : cur + 1;
            sb = (sb == 2) ? 0 : sb + 1;
        }

        // drain all in-flight stages; ensure every wave is done reading LDS
        // before the next part's prologue overwrites the buffers.
        asm volatile("s_waitcnt vmcnt(0)" ::: "memory");
        __builtin_amdgcn_s_barrier();
        asm volatile("" ::: "memory");

        float inv[4];
#pragma unroll
        for (int r = 0; r < 4; r++) inv[r] = 1.0f / __shfl(l, hi * 4 + r);
        int qrow = qw + hi * 4;
#pragma unroll
        for (int dt = 0; dt < 4; dt++)
#pragma unroll
            for (int r = 0; r < 4; r++)
                Oa[(size_t)(qrow + r) * 2048 + h * 64 + dt * 16 + lo] =
                    f2b(O[dt][r] * inv[r]);
    }
}

extern "C" void kernel_launch(void* const* d_in, const int* in_sizes, int n_in,
                              void* d_out, int out_size, void* d_ws, size_t ws_size,
                              hipStream_t stream) {
    const float* x  = (const float*)d_in[0];
    const float* R  = (const float*)d_in[1];
    // d_in[2] = mask: unused (causal mask applied analytically)
    const float* wq = (const float*)d_in[3];
    const float* wk = (const float*)d_in[4];
    const float* wv = (const float*)d_in[5];
    const float* wo = (const float*)d_in[6];

    float* out0 = (float*)d_out;
    float* outK = out0 + (size_t)2048 * 2048;
    float* outV = outK + (size_t)32 * 2048 * 64;

    char* ws = (char*)d_ws;
    unsigned short* BTall = (unsigned short*)(ws);               // 12 MB [3072][2048]
    unsigned short* woT = (unsigned short*)(ws + 12582912);      // 8 MB
    unsigned short* Qb  = (unsigned short*)(ws + 20971520);      // 8 MB
    unsigned short* Kb  = (unsigned short*)(ws + 29360128);      // 2 MB
    unsigned short* Vb  = (unsigned short*)(ws + 31457280);      // 2 MB
    unsigned short* VtT = (unsigned short*)(ws + 33554432);      // 2 MB [512][2048]
    unsigned short* Ob  = (unsigned short*)(ws + 35651584);      // 8 MB
    float* cosT = (float*)(ws + 44040192);                       // 256 KB
    float* sinT = (float*)(ws + 44302336);                       // 256 KB
    unsigned short* xb  = (unsigned short*)(ws + 44564480);      // 8 MB

    cvt_f32_bf16<<<2048, 256, 0, stream>>>(x, xb);
    transpose_f32_bf16<<<dim3(32, 32), 256, 0, stream>>>(wq, BTall, 2048, 2048);
    transpose_f32_bf16<<<dim3(8, 32), 256, 0, stream>>>(wk, BTall + (size_t)2048 * 2048, 2048, 512);
    transpose_f32_bf16<<<dim3(8, 32), 256, 0, stream>>>(wv, BTall + (size_t)2560 * 2048, 2048, 512);
    transpose_f32_bf16<<<dim3(32, 32), 256, 0, stream>>>(wo, woT, 2048, 2048);
    rope_tables<<<256, 256, 0, stream>>>(R, cosT, sinT);

    gemm_qkv<<<dim3(48, 16), 256, 0, stream>>>(xb, BTall, Qb, Kb, Vb, cosT, sinT, outK, outV);

    transpose_bf16<<<dim3(8, 32), 256, 0, stream>>>(Vb, VtT, 2048, 512);

    attn<<<dim3(32, 16), 256, 0, stream>>>(Qb, Kb, VtT, Ob);

    gemm_out<<<dim3(32, 16), 256, 0, stream>>>(Ob, woT, out0, 2048, 2048, 2048);
}

// Round 11
// 165.038 us; speedup vs baseline: 1.2329x; 1.0345x over previous
//
#include <hip/hip_runtime.h>

typedef __attribute__((ext_vector_type(8))) short s16x8;
typedef __attribute__((ext_vector_type(4))) float f32x4;

#define SCALE 0.125f
#define LOG2E 1.4426950408889634f
#define QSC (SCALE * LOG2E)

__device__ inline float b2f(unsigned short u) {
    union { unsigned int i; float f; } x; x.i = ((unsigned int)u) << 16; return x.f;
}
__device__ inline unsigned short f2b(float f) {
    union { float f; unsigned int i; } x; x.f = f;
    unsigned int i = x.i;
    unsigned int r = (i + 0x7FFFu + ((i >> 16) & 1u)) >> 16;
    return (unsigned short)r;
}

// async global->LDS, 16B per lane; lds base must be wave-uniform.
typedef const __attribute__((address_space(1))) unsigned int guint;
typedef __attribute__((address_space(3))) unsigned int luint;
__device__ __forceinline__ void gll16(const void* g, void* l) {
    __builtin_amdgcn_global_load_lds((guint*)g, (luint*)l, 16, 0, 0);
}

// counted-vmcnt barrier: allow newest N loads to stay in flight across it.
#define CBAR(N)                                           \
    do {                                                  \
        asm volatile("s_waitcnt vmcnt(" #N ")" ::: "memory"); \
        __builtin_amdgcn_s_barrier();                     \
        asm volatile("" ::: "memory");                    \
    } while (0)

// ================= merged prep kernel (z-task switch) =================
// z0: wq^T   z1: wo^T   z2: wk^T   z3: wv^T   z4: x f32->bf16   z5: rope tables
__device__ __forceinline__ void transpose_body(
    const float* __restrict__ in, unsigned short* __restrict__ out,
    int R, int C, unsigned short (*tile)[72]) {
    int tc = blockIdx.x * 64, tr = blockIdx.y * 64;
    int t = threadIdx.x;
    int r = t >> 2, cq = (t & 3) * 16;
    const float* src = in + (size_t)(tr + r) * C + tc + cq;
#pragma unroll
    for (int j = 0; j < 16; j += 4) {
        f32x4 v = *(const f32x4*)(src + j);
        tile[r][cq + j]     = f2b(v[0]);
        tile[r][cq + j + 1] = f2b(v[1]);
        tile[r][cq + j + 2] = f2b(v[2]);
        tile[r][cq + j + 3] = f2b(v[3]);
    }
    __syncthreads();
    int oc = t >> 2, rq = (t & 3) * 16;
    s16x8 w0, w1;
#pragma unroll
    for (int j = 0; j < 8; j++) {
        w0[j] = (short)tile[rq + j][oc];
        w1[j] = (short)tile[rq + 8 + j][oc];
    }
    s16x8* dst = (s16x8*)(out + (size_t)(tc + oc) * R + tr + rq);
    dst[0] = w0; dst[1] = w1;
}

__global__ __launch_bounds__(256) void prep(
    const float* __restrict__ x, const float* __restrict__ R,
    const float* __restrict__ wq, const float* __restrict__ wk,
    const float* __restrict__ wv, const float* __restrict__ wo,
    unsigned short* __restrict__ xb, unsigned short* __restrict__ BTall,
    unsigned short* __restrict__ woT, float* __restrict__ cosT,
    float* __restrict__ sinT) {
    __shared__ unsigned short tile[64][72];
    int z = blockIdx.z;
    if (z == 0) {
        transpose_body(wq, BTall, 2048, 2048, tile);
    } else if (z == 1) {
        transpose_body(wo, woT, 2048, 2048, tile);
    } else if (z == 2) {
        if (blockIdx.x < 8)
            transpose_body(wk, BTall + (size_t)2048 * 2048, 2048, 512, tile);
    } else if (z == 3) {
        if (blockIdx.x < 8)
            transpose_body(wv, BTall + (size_t)2560 * 2048, 2048, 512, tile);
    } else if (z == 4) {
        int bid = blockIdx.y * 32 + blockIdx.x;
        int i = (bid * 256 + threadIdx.x) * 16;
#pragma unroll
        for (int half = 0; half < 2; half++) {
            int ii = i + half * 8;
            f32x4 a = *(const f32x4*)(x + ii);
            f32x4 b = *(const f32x4*)(x + ii + 4);
            s16x8 o;
            o[0] = (short)f2b(a[0]); o[1] = (short)f2b(a[1]);
            o[2] = (short)f2b(a[2]); o[3] = (short)f2b(a[3]);
            o[4] = (short)f2b(b[0]); o[5] = (short)f2b(b[1]);
            o[6] = (short)f2b(b[2]); o[7] = (short)f2b(b[3]);
            *(s16x8*)(xb + ii) = o;
        }
    } else {
        int bid = blockIdx.y * 32 + blockIdx.x;
        if (bid < 256) {
            int idx = bid * 256 + threadIdx.x;  // L*32
            int l = idx >> 5, i = idx & 31;
            size_t base = (size_t)l * 4096;
            cosT[idx] = R[base + (size_t)(2 * i) * 64 + 2 * i];
            sinT[idx] = R[base + (size_t)(2 * i + 1) * 64 + 2 * i];
        }
    }
}

// ==== GEMM core: BM=128 x BN=64 x BK=32, 4 LDS buffers, K-loop unrolled
// x4 so all buffer indices are compile-time (ds_read offset-imm folding,
// loop-invariant gll16 addresses). Stage 2 tiles ahead; CBAR(3) keeps the
// newest stage (3 loads) in flight across the barrier.

// ---- fused QKV GEMM + RoPE epilogue (+ K/V f32 outputs) ----
__global__ __launch_bounds__(256) void gemm_qkv(
    const unsigned short* __restrict__ A, const unsigned short* __restrict__ BT,
    unsigned short* __restrict__ Qb, unsigned short* __restrict__ Kb,
    unsigned short* __restrict__ Vb, const float* __restrict__ cosT,
    const float* __restrict__ sinT, float* __restrict__ outK,
    float* __restrict__ outV) {
    const int K = 2048;
    __shared__ unsigned short As[4][128 * 32];
    __shared__ unsigned short Bs[4][64 * 32];
    int t = threadIdx.x;
    int w = t >> 6, lane = t & 63, lo = lane & 15, hi = lane >> 4;
    int m0 = blockIdx.y * 128, n0 = blockIdx.x * 64;
    int wr = w >> 1, wc = w & 1;
    int srow = lane >> 2, scol = (lane & 3) * 8;

    const unsigned short* gA = A + (size_t)(m0 + w * 16 + srow) * K + scol;
    const unsigned short* gB = BT + (size_t)(n0 + w * 16 + srow) * K + scol;

#define GSTAGE(buf, kk)                                                  \
    {                                                                    \
        gll16(gA + (kk), &As[buf][(w * 16) * 32]);                       \
        gll16(gA + (size_t)64 * K + (kk), &As[buf][(64 + w * 16) * 32]); \
        gll16(gB + (kk), &Bs[buf][(w * 16) * 32]);                       \
    }

    f32x4 acc[4][2] = {};

    GSTAGE(0, 0);
    GSTAGE(1, 32);

    for (int kq = 0; kq < K; kq += 128) {
#pragma unroll
        for (int qi = 0; qi < 4; qi++) {
            CBAR(3);
            int kk = kq + qi * 32;
            if (kk + 64 < K) GSTAGE((qi ^ 2), kk + 64);
            s16x8 af[4], bfr[2];
#pragma unroll
            for (int i = 0; i < 4; i++)
                af[i] = *(const s16x8*)&As[qi][(wr * 64 + i * 16 + lo) * 32 + hi * 8];
#pragma unroll
            for (int j = 0; j < 2; j++)
                bfr[j] = *(const s16x8*)&Bs[qi][(wc * 32 + j * 16 + lo) * 32 + hi * 8];
#pragma unroll
            for (int i = 0; i < 4; i++)
#pragma unroll
                for (int j = 0; j < 2; j++)
                    acc[i][j] = __builtin_amdgcn_mfma_f32_16x16x32_bf16(
                        af[i], bfr[j], acc[i][j], 0, 0, 0);
        }
    }

    if (n0 < 2048) {  // ---- Q: rope + QSC ----
#pragma unroll
        for (int i = 0; i < 4; i++)
#pragma unroll
            for (int j = 0; j < 2; j++) {
                int colb = n0 + wc * 32 + j * 16 + lo;
                int d = colb & 63;
                float sgn = (d & 1) ? 1.0f : -1.0f;
                int ip = d >> 1;
#pragma unroll
                for (int r = 0; r < 4; r++) {
                    int row = m0 + wr * 64 + i * 16 + hi * 4 + r;
                    float v = acc[i][j][r];
                    float p = __shfl_xor(v, 1);
                    float c = cosT[row * 32 + ip], s = sinT[row * 32 + ip];
                    float o = (c * v + sgn * s * p) * QSC;
                    Qb[(size_t)row * 2048 + colb] = f2b(o);
                }
            }
    } else if (n0 < 2560) {  // ---- K: rope + repeated f32 out ----
        int cb = n0 - 2048;
#pragma unroll
        for (int i = 0; i < 4; i++)
#pragma unroll
            for (int j = 0; j < 2; j++) {
                int colb = cb + wc * 32 + j * 16 + lo;
                int d = colb & 63;
                int kvh2 = colb >> 6;
                float sgn = (d & 1) ? 1.0f : -1.0f;
                int ip = d >> 1;
#pragma unroll
                for (int r = 0; r < 4; r++) {
                    int row = m0 + wr * 64 + i * 16 + hi * 4 + r;
                    float v = acc[i][j][r];
                    float p = __shfl_xor(v, 1);
                    float c = cosT[row * 32 + ip], s = sinT[row * 32 + ip];
                    float o = c * v + sgn * s * p;
                    Kb[(size_t)row * 512 + colb] = f2b(o);
#pragma unroll
                    for (int rep = 0; rep < 4; rep++) {
                        int h2 = kvh2 * 4 + rep;
                        outK[((size_t)h2 * 2048 + row) * 64 + d] = o;
                    }
                }
            }
    } else {  // ---- V: plain bf16 + repeated f32 out ----
        int cb = n0 - 2560;
#pragma unroll
        for (int i = 0; i < 4; i++)
#pragma unroll
            for (int j = 0; j < 2; j++) {
                int colb = cb + wc * 32 + j * 16 + lo;
                int d = colb & 63;
                int kvh2 = colb >> 6;
#pragma unroll
                for (int r = 0; r < 4; r++) {
                    int row = m0 + wr * 64 + i * 16 + hi * 4 + r;
                    float v = acc[i][j][r];
                    Vb[(size_t)row * 512 + colb] = f2b(v);
#pragma unroll
                    for (int rep = 0; rep < 4; rep++) {
                        int h2 = kvh2 * 4 + rep;
                        outV[((size_t)h2 * 2048 + row) * 64 + d] = v;
                    }
                }
            }
    }
#undef GSTAGE
}

// -------- output GEMM: A[M][K] bf16, BT[N][K] bf16 -> C[M][N] f32 --------
__global__ __launch_bounds__(256) void gemm_out(
    const unsigned short* __restrict__ A, const unsigned short* __restrict__ BT,
    float* __restrict__ C, int M, int N, int K) {
    __shared__ unsigned short As[4][128 * 32];
    __shared__ unsigned short Bs[4][64 * 32];
    int t = threadIdx.x;
    int w = t >> 6, lane = t & 63, lo = lane & 15, hi = lane >> 4;
    int m0 = blockIdx.y * 128, n0 = blockIdx.x * 64;
    int wr = w >> 1, wc = w & 1;
    int srow = lane >> 2, scol = (lane & 3) * 8;

    const unsigned short* gA = A + (size_t)(m0 + w * 16 + srow) * K + scol;
    const unsigned short* gB = BT + (size_t)(n0 + w * 16 + srow) * K + scol;

#define GSTAGE(buf, kk)                                                  \
    {                                                                    \
        gll16(gA + (kk), &As[buf][(w * 16) * 32]);                       \
        gll16(gA + (size_t)64 * K + (kk), &As[buf][(64 + w * 16) * 32]); \
        gll16(gB + (kk), &Bs[buf][(w * 16) * 32]);                       \
    }

    f32x4 acc[4][2] = {};

    GSTAGE(0, 0);
    GSTAGE(1, 32);

    for (int kq = 0; kq < K; kq += 128) {
#pragma unroll
        for (int qi = 0; qi < 4; qi++) {
            CBAR(3);
            int kk = kq + qi * 32;
            if (kk + 64 < K) GSTAGE((qi ^ 2), kk + 64);
            s16x8 af[4], bfr[2];
#pragma unroll
            for (int i = 0; i < 4; i++)
                af[i] = *(const s16x8*)&As[qi][(wr * 64 + i * 16 + lo) * 32 + hi * 8];
#pragma unroll
            for (int j = 0; j < 2; j++)
                bfr[j] = *(const s16x8*)&Bs[qi][(wc * 32 + j * 16 + lo) * 32 + hi * 8];
#pragma unroll
            for (int i = 0; i < 4; i++)
#pragma unroll
                for (int j = 0; j < 2; j++)
                    acc[i][j] = __builtin_amdgcn_mfma_f32_16x16x32_bf16(
                        af[i], bfr[j], acc[i][j], 0, 0, 0);
        }
    }
#pragma unroll
    for (int i = 0; i < 4; i++)
#pragma unroll
        for (int j = 0; j < 2; j++)
#pragma unroll
            for (int r = 0; r < 4; r++) {
                int row = m0 + wr * 64 + i * 16 + hi * 4 + r;
                int col = n0 + wc * 32 + j * 16 + lo;
                C[(size_t)row * N + col] = acc[i][j][r];
            }
#undef GSTAGE
}

// ------------- transpose bf16: in[R][C] -> out[C][R] (for V^T) -------------
__global__ __launch_bounds__(256) void transpose_bf16(
    const unsigned short* __restrict__ in, unsigned short* __restrict__ out,
    int R, int C) {
    __shared__ unsigned short tile[64][72];
    int tc = blockIdx.x * 64, tr = blockIdx.y * 64;
    int t = threadIdx.x;
    int r = t >> 2, cq = (t & 3) * 16;
    const s16x8* src = (const s16x8*)(in + (size_t)(tr + r) * C + tc + cq);
    s16x8 v0 = src[0], v1 = src[1];
    *(s16x8*)&tile[r][cq] = v0;
    *(s16x8*)&tile[r][cq + 8] = v1;
    __syncthreads();
    int oc = t >> 2, rq = (t & 3) * 16;
    s16x8 w0, w1;
#pragma unroll
    for (int j = 0; j < 8; j++) {
        w0[j] = (short)tile[rq + j][oc];
        w1[j] = (short)tile[rq + 8 + j][oc];
    }
    s16x8* dst = (s16x8*)(out + (size_t)(tc + oc) * R + tr + rq);
    dst[0] = w0; dst[1] = w1;
}

// ====================== flash attention (causal) ======================
// 512 EQUAL blocks: grid (32 h, 16 p); each 4-wave block serially handles
// strip pair (p, 31-p) of 64 q-rows (16 rows/wave) -> exactly 33 k-tiles
// per block, all blocks identical, 2 blocks/CU resident, no tail.
// Triple-buffered K/V^T LDS, gll16-staged (XOR-preswizzled source),
// counted vmcnt(4) across raw barriers. Swapped QK^T; in-reg softmax with
// defer-max; cvt_pk + shfl repack into PV A-fragment.

__device__ __forceinline__ s16x8 repack_p(
    const unsigned int pk[4][2], int c, int src1, bool selB) {
    int src2 = src1 + 16;
    unsigned int tA0 = pk[2 * c][0], tA1 = pk[2 * c][1];
    unsigned int tB0 = pk[2 * c + 1][0], tB1 = pk[2 * c + 1][1];
    unsigned int a0 = __shfl((int)tA0, src1), a1 = __shfl((int)tA1, src1);
    unsigned int a2 = __shfl((int)tA0, src2), a3 = __shfl((int)tA1, src2);
    unsigned int b0 = __shfl((int)tB0, src1), b1 = __shfl((int)tB1, src1);
    unsigned int b2 = __shfl((int)tB0, src2), b3 = __shfl((int)tB1, src2);
    union { s16x8 v; unsigned int u[4]; } x;
    x.u[0] = selB ? b0 : a0;
    x.u[1] = selB ? b1 : a1;
    x.u[2] = selB ? b2 : a2;
    x.u[3] = selB ? b3 : a3;
    return x.v;
}

__global__ __launch_bounds__(256) void attn(
    const unsigned short* __restrict__ Q, const unsigned short* __restrict__ Kr,
    const unsigned short* __restrict__ Vt, unsigned short* __restrict__ Oa) {
    __shared__ unsigned short KL[3][64 * 64];
    __shared__ unsigned short VL[3][64 * 64];

    int h = blockIdx.x;
    int kvh = h >> 2;
    int p = blockIdx.y;  // 0..15 -> strips (p, 31-p)
    int t = threadIdx.x, wave = t >> 6, lane = t & 63, lo = lane & 15, hi = lane >> 4;

    int srow = wave * 16 + (lane >> 3);
    int sc = lane & 7;
    int src1 = lo + ((hi & 1) << 5);
    bool selB = hi >= 2;
    int swz = lo & 7;
    int qrel = wave * 16 + lo;  // within-diag-tile q offset

#define STAGE_KV(buf, kb)                                                          \
    {                                                                              \
        _Pragma("unroll")                                                          \
        for (int j = 0; j < 2; j++) {                                              \
            int r = srow + j * 8;                                                  \
            gll16(Kr + (size_t)((kb) * 64 + r) * 512 + kvh * 64 +                  \
                      ((sc ^ (r & 7)) * 8),                                        \
                  &KL[buf][(wave * 16 + j * 8) * 64]);                             \
            gll16(Vt + (size_t)(kvh * 64 + r) * 2048 + (kb) * 64 +                 \
                      ((sc ^ (r & 7)) * 8),                                        \
                  &VL[buf][(wave * 16 + j * 8) * 64]);                             \
        }                                                                          \
    }

#pragma unroll 1
    for (int part = 0; part < 2; ++part) {
        int s = part ? (31 - p) : p;  // 64-row strip index; tiles 0..s
        int qw = s * 64 + wave * 16;

        s16x8 qf[2];
#pragma unroll
        for (int hf = 0; hf < 2; hf++)
            qf[hf] = *(const s16x8*)(Q + (size_t)(qw + lo) * 2048 +
                                     h * 64 + hf * 32 + hi * 8);

        f32x4 O[4] = {};
        float m = -1e30f, l = 0.f;

        STAGE_KV(0, 0);
        STAGE_KV(1, (s > 0 ? 1 : 0));
        int cur = 0, sb = 2;

        for (int kb = 0; kb <= s; ++kb) {
            CBAR(4);
            int nx = (kb + 2 > s) ? s : kb + 2;
            STAGE_KV(sb, nx);

            s16x8 kf[4][2];
#pragma unroll
            for (int tt = 0; tt < 4; tt++)
#pragma unroll
                for (int hf = 0; hf < 2; hf++) {
                    int ch = (hf * 4 + hi) ^ swz;
                    kf[tt][hf] = *(const s16x8*)&KL[cur][(tt * 16 + lo) * 64 + ch * 8];
                }
            s16x8 vf[2][4];
#pragma unroll
            for (int c = 0; c < 2; c++)
#pragma unroll
                for (int dt = 0; dt < 4; dt++) {
                    int ch = (c * 4 + hi) ^ swz;
                    vf[c][dt] = *(const s16x8*)&VL[cur][(dt * 16 + lo) * 64 + ch * 8];
                }

            f32x4 s0[4];
            __builtin_amdgcn_s_setprio(1);
#pragma unroll
            for (int tt = 0; tt < 4; tt++) {
                f32x4 z0 = {};
                z0 = __builtin_amdgcn_mfma_f32_16x16x32_bf16(kf[tt][0], qf[0], z0, 0, 0, 0);
                z0 = __builtin_amdgcn_mfma_f32_16x16x32_bf16(kf[tt][1], qf[1], z0, 0, 0, 0);
                s0[tt] = z0;
            }
            __builtin_amdgcn_s_setprio(0);

            if (kb == s) {  // diagonal tile: causal mask
#pragma unroll
                for (int tt = 0; tt < 4; tt++)
#pragma unroll
                    for (int r = 0; r < 4; r++) {
                        int kg = tt * 16 + hi * 4 + r;
                        if (kg > qrel) s0[tt][r] = -1e30f;
                    }
            }

            // ---- online softmax with defer-max (THR = 8, log2 units) ----
            float mx = s0[0][0];
#pragma unroll
            for (int tt = 0; tt < 4; tt++)
#pragma unroll
                for (int r = 0; r < 4; r++) mx = fmaxf(mx, s0[tt][r]);
            mx = fmaxf(mx, __shfl_xor(mx, 16));
            mx = fmaxf(mx, __shfl_xor(mx, 32));

            if (!__all(mx - m <= 8.0f)) {
                float mn = fmaxf(m, mx);
                float al = __builtin_amdgcn_exp2f(m - mn);
                m = mn;
                l *= al;
                float alr[4];
#pragma unroll
                for (int r = 0; r < 4; r++) alr[r] = __shfl(al, hi * 4 + r);
#pragma unroll
                for (int dt = 0; dt < 4; dt++)
#pragma unroll
                    for (int r = 0; r < 4; r++) O[dt][r] *= alr[r];
            }

            unsigned int pk[4][2];
            float rs = 0.f;
#pragma unroll
            for (int tt = 0; tt < 4; tt++) {
#pragma unroll
                for (int r = 0; r < 4; r++) {
                    float pv = __builtin_amdgcn_exp2f(s0[tt][r] - m);
                    s0[tt][r] = pv;
                    rs += pv;
                }
                unsigned int a, b;
                asm("v_cvt_pk_bf16_f32 %0, %1, %2" : "=v"(a) : "v"(s0[tt][0]), "v"(s0[tt][1]));
                asm("v_cvt_pk_bf16_f32 %0, %1, %2" : "=v"(b) : "v"(s0[tt][2]), "v"(s0[tt][3]));
                pk[tt][0] = a; pk[tt][1] = b;
            }
            rs += __shfl_xor(rs, 16);
            rs += __shfl_xor(rs, 32);
            l += rs;

#pragma unroll
            for (int c = 0; c < 2; c++) {
                s16x8 pa = repack_p(pk, c, src1, selB);
                __builtin_amdgcn_s_setprio(1);
#pragma unroll
                for (int dt = 0; dt < 4; dt++)
                    O[dt] = __builtin_amdgcn_mfma_f32_16x16x32_bf16(pa, vf[c][dt], O[dt], 0, 0, 0);
                __builtin_amdgcn_s_setprio(0);
            }

            cur = (cur == 2) ? 0 : cur + 1;
            sb = (sb == 2) ? 0 : sb + 1;
        }

        // drain all in-flight stages; ensure every wave is done reading LDS
        // before the next part's prologue overwrites the buffers.
        asm volatile("s_waitcnt vmcnt(0)" ::: "memory");
        __builtin_amdgcn_s_barrier();
        asm volatile("" ::: "memory");

        float inv[4];
#pragma unroll
        for (int r = 0; r < 4; r++) inv[r] = 1.0f / __shfl(l, hi * 4 + r);
        int qrow = qw + hi * 4;
#pragma unroll
        for (int dt = 0; dt < 4; dt++)
#pragma unroll
            for (int r = 0; r < 4; r++)
                Oa[(size_t)(qrow + r) * 2048 + h * 64 + dt * 16 + lo] =
                    f2b(O[dt][r] * inv[r]);
    }
}

extern "C" void kernel_launch(void* const* d_in, const int* in_sizes, int n_in,
                              void* d_out, int out_size, void* d_ws, size_t ws_size,
                              hipStream_t stream) {
    const float* x  = (const float*)d_in[0];
    const float* R  = (const float*)d_in[1];
    // d_in[2] = mask: unused (causal mask applied analytically)
    const float* wq = (const float*)d_in[3];
    const float* wk = (const float*)d_in[4];
    const float* wv = (const float*)d_in[5];
    const float* wo = (const float*)d_in[6];

    float* out0 = (float*)d_out;
    float* outK = out0 + (size_t)2048 * 2048;
    float* outV = outK + (size_t)32 * 2048 * 64;

    char* ws = (char*)d_ws;
    unsigned short* BTall = (unsigned short*)(ws);               // 12 MB [3072][2048]
    unsigned short* woT = (unsigned short*)(ws + 12582912);      // 8 MB
    unsigned short* Qb  = (unsigned short*)(ws + 20971520);      // 8 MB
    unsigned short* Kb  = (unsigned short*)(ws + 29360128);      // 2 MB
    unsigned short* Vb  = (unsigned short*)(ws + 31457280);      // 2 MB
    unsigned short* VtT = (unsigned short*)(ws + 33554432);      // 2 MB [512][2048]
    unsigned short* Ob  = (unsigned short*)(ws + 35651584);      // 8 MB
    float* cosT = (float*)(ws + 44040192);                       // 256 KB
    float* sinT = (float*)(ws + 44302336);                       // 256 KB
    unsigned short* xb  = (unsigned short*)(ws + 44564480);      // 8 MB

    prep<<<dim3(32, 32, 6), 256, 0, stream>>>(x, R, wq, wk, wv, wo, xb, BTall,
                                              woT, cosT, sinT);

    gemm_qkv<<<dim3(48, 16), 256, 0, stream>>>(xb, BTall, Qb, Kb, Vb, cosT, sinT, outK, outV);

    transpose_bf16<<<dim3(8, 32), 256, 0, stream>>>(Vb, VtT, 2048, 512);

    attn<<<dim3(32, 16), 256, 0, stream>>>(Qb, Kb, VtT, Ob);

    gemm_out<<<dim3(32, 16), 256, 0, stream>>>(Ob, woT, out0, 2048, 2048, 2048);
}

// Round 12
// 162.878 us; speedup vs baseline: 1.2493x; 1.0133x over previous
//
#include <hip/hip_runtime.h>

typedef __attribute__((ext_vector_type(8))) short s16x8;
typedef __attribute__((ext_vector_type(4))) float f32x4;

#define SCALE 0.125f
#define LOG2E 1.4426950408889634f
#define QSC (SCALE * LOG2E)

__device__ inline float b2f(unsigned short u) {
    union { unsigned int i; float f; } x; x.i = ((unsigned int)u) << 16; return x.f;
}
__device__ inline unsigned short f2b(float f) {
    union { float f; unsigned int i; } x; x.f = f;
    unsigned int i = x.i;
    unsigned int r = (i + 0x7FFFu + ((i >> 16) & 1u)) >> 16;
    return (unsigned short)r;
}

// async global->LDS, 16B per lane; lds base must be wave-uniform.
typedef const __attribute__((address_space(1))) unsigned int guint;
typedef __attribute__((address_space(3))) unsigned int luint;
__device__ __forceinline__ void gll16(const void* g, void* l) {
    __builtin_amdgcn_global_load_lds((guint*)g, (luint*)l, 16, 0, 0);
}

// counted-vmcnt barrier: allow newest N loads to stay in flight across it.
#define CBAR(N)                                           \
    do {                                                  \
        asm volatile("s_waitcnt vmcnt(" #N ")" ::: "memory"); \
        __builtin_amdgcn_s_barrier();                     \
        asm volatile("" ::: "memory");                    \
    } while (0)

// ================= merged prep kernel (z-task switch) =================
__device__ __forceinline__ void transpose_body(
    const float* __restrict__ in, unsigned short* __restrict__ out,
    int R, int C, unsigned short (*tile)[72]) {
    int tc = blockIdx.x * 64, tr = blockIdx.y * 64;
    int t = threadIdx.x;
    int r = t >> 2, cq = (t & 3) * 16;
    const float* src = in + (size_t)(tr + r) * C + tc + cq;
#pragma unroll
    for (int j = 0; j < 16; j += 4) {
        f32x4 v = *(const f32x4*)(src + j);
        tile[r][cq + j]     = f2b(v[0]);
        tile[r][cq + j + 1] = f2b(v[1]);
        tile[r][cq + j + 2] = f2b(v[2]);
        tile[r][cq + j + 3] = f2b(v[3]);
    }
    __syncthreads();
    int oc = t >> 2, rq = (t & 3) * 16;
    s16x8 w0, w1;
#pragma unroll
    for (int j = 0; j < 8; j++) {
        w0[j] = (short)tile[rq + j][oc];
        w1[j] = (short)tile[rq + 8 + j][oc];
    }
    s16x8* dst = (s16x8*)(out + (size_t)(tc + oc) * R + tr + rq);
    dst[0] = w0; dst[1] = w1;
}

__global__ __launch_bounds__(256) void prep(
    const float* __restrict__ x, const float* __restrict__ R,
    const float* __restrict__ wq, const float* __restrict__ wk,
    const float* __restrict__ wv, const float* __restrict__ wo,
    unsigned short* __restrict__ xb, unsigned short* __restrict__ BTall,
    unsigned short* __restrict__ woT, float* __restrict__ cosT,
    float* __restrict__ sinT) {
    __shared__ unsigned short tile[64][72];
    int z = blockIdx.z;
    if (z == 0) {
        transpose_body(wq, BTall, 2048, 2048, tile);
    } else if (z == 1) {
        transpose_body(wo, woT, 2048, 2048, tile);
    } else if (z == 2) {
        if (blockIdx.x < 8)
            transpose_body(wk, BTall + (size_t)2048 * 2048, 2048, 512, tile);
    } else if (z == 3) {
        if (blockIdx.x < 8)
            transpose_body(wv, BTall + (size_t)2560 * 2048, 2048, 512, tile);
    } else if (z == 4) {
        int bid = blockIdx.y * 32 + blockIdx.x;
        int i = (bid * 256 + threadIdx.x) * 16;
#pragma unroll
        for (int half = 0; half < 2; half++) {
            int ii = i + half * 8;
            f32x4 a = *(const f32x4*)(x + ii);
            f32x4 b = *(const f32x4*)(x + ii + 4);
            s16x8 o;
            o[0] = (short)f2b(a[0]); o[1] = (short)f2b(a[1]);
            o[2] = (short)f2b(a[2]); o[3] = (short)f2b(a[3]);
            o[4] = (short)f2b(b[0]); o[5] = (short)f2b(b[1]);
            o[6] = (short)f2b(b[2]); o[7] = (short)f2b(b[3]);
            *(s16x8*)(xb + ii) = o;
        }
    } else {
        int bid = blockIdx.y * 32 + blockIdx.x;
        if (bid < 256) {
            int idx = bid * 256 + threadIdx.x;  // L*32
            int l = idx >> 5, i = idx & 31;
            size_t base = (size_t)l * 4096;
            cosT[idx] = R[base + (size_t)(2 * i) * 64 + 2 * i];
            sinT[idx] = R[base + (size_t)(2 * i + 1) * 64 + 2 * i];
        }
    }
}

// ==== GEMM core v2: 64(M) x 128(N) tile, 2 waves, 64x64 per wave (4x4
// acc -> 16 MFMA per 8 ds_read_b128). 3 LDS buffers (12KB each), stage-2-
// ahead, CBAR(6). Staging uses linear LDS dest + XOR-preswizzled global
// source chunk (chunk ^= row&3); reads apply the same XOR -> ~2-way
// conflicts instead of ~8-way.

// ---- fused QKV GEMM + RoPE epilogue (+ K/V f32 outputs) ----
__global__ __launch_bounds__(128) void gemm_qkv(
    const unsigned short* __restrict__ A, const unsigned short* __restrict__ BT,
    unsigned short* __restrict__ Qb, unsigned short* __restrict__ Kb,
    unsigned short* __restrict__ Vb, const float* __restrict__ cosT,
    const float* __restrict__ sinT, float* __restrict__ outK,
    float* __restrict__ outV) {
    const int K = 2048;
    __shared__ unsigned short As[3][64 * 32];
    __shared__ unsigned short Bs[3][128 * 32];
    int t = threadIdx.x;
    int w = t >> 6, lane = t & 63, lo = lane & 15, hi = lane >> 4;
    int m0 = blockIdx.y * 64, n0 = blockIdx.x * 128;
    int sr = lane >> 2;                    // row within 16-row gll block
    int scol = ((lane & 3) ^ (sr & 3)) * 8;  // preswizzled source chunk

    const unsigned short* gA = A + (size_t)(m0 + w * 32 + sr) * K + scol;
    const unsigned short* gB = BT + (size_t)(n0 + w * 64 + sr) * K + scol;
    int rsw = (hi ^ (lo & 3)) * 8;         // swizzled read chunk

#define GSTAGE(buf, kk)                                                   \
    {                                                                     \
        gll16(gA + (kk), &As[buf][(w * 32) * 32]);                        \
        gll16(gA + (size_t)16 * K + (kk), &As[buf][(w * 32 + 16) * 32]);  \
        gll16(gB + (kk), &Bs[buf][(w * 64) * 32]);                        \
        gll16(gB + (size_t)16 * K + (kk), &Bs[buf][(w * 64 + 16) * 32]);  \
        gll16(gB + (size_t)32 * K + (kk), &Bs[buf][(w * 64 + 32) * 32]);  \
        gll16(gB + (size_t)48 * K + (kk), &Bs[buf][(w * 64 + 48) * 32]);  \
    }

    f32x4 acc[4][4] = {};

    GSTAGE(0, 0);
    GSTAGE(1, 32);
    int cur = 0, sb = 2;

    for (int k0 = 0; k0 < K; k0 += 32) {
        if (k0 + 64 < K) {
            CBAR(6);
            GSTAGE(sb, k0 + 64);
        } else if (k0 + 32 < K) {
            CBAR(6);
        } else {
            CBAR(0);
        }
        s16x8 af[4], bfr[4];
#pragma unroll
        for (int i = 0; i < 4; i++)
            af[i] = *(const s16x8*)&As[cur][(i * 16 + lo) * 32 + rsw];
#pragma unroll
        for (int j = 0; j < 4; j++)
            bfr[j] = *(const s16x8*)&Bs[cur][(w * 64 + j * 16 + lo) * 32 + rsw];
#pragma unroll
        for (int i = 0; i < 4; i++)
#pragma unroll
            for (int j = 0; j < 4; j++)
                acc[i][j] = __builtin_amdgcn_mfma_f32_16x16x32_bf16(
                    af[i], bfr[j], acc[i][j], 0, 0, 0);
        cur = (cur == 2) ? 0 : cur + 1;
        sb = (sb == 2) ? 0 : sb + 1;
    }

    if (n0 < 2048) {  // ---- Q: rope + QSC ----
#pragma unroll
        for (int i = 0; i < 4; i++)
#pragma unroll
            for (int j = 0; j < 4; j++) {
                int colb = n0 + w * 64 + j * 16 + lo;
                int d = colb & 63;
                float sgn = (d & 1) ? 1.0f : -1.0f;
                int ip = d >> 1;
#pragma unroll
                for (int r = 0; r < 4; r++) {
                    int row = m0 + i * 16 + hi * 4 + r;
                    float v = acc[i][j][r];
                    float p = __shfl_xor(v, 1);
                    float c = cosT[row * 32 + ip], s = sinT[row * 32 + ip];
                    float o = (c * v + sgn * s * p) * QSC;
                    Qb[(size_t)row * 2048 + colb] = f2b(o);
                }
            }
    } else if (n0 < 2560) {  // ---- K: rope + repeated f32 out ----
        int cb = n0 - 2048;
#pragma unroll
        for (int i = 0; i < 4; i++)
#pragma unroll
            for (int j = 0; j < 4; j++) {
                int colb = cb + w * 64 + j * 16 + lo;
                int d = colb & 63;
                int kvh2 = colb >> 6;
                float sgn = (d & 1) ? 1.0f : -1.0f;
                int ip = d >> 1;
#pragma unroll
                for (int r = 0; r < 4; r++) {
                    int row = m0 + i * 16 + hi * 4 + r;
                    float v = acc[i][j][r];
                    float p = __shfl_xor(v, 1);
                    float c = cosT[row * 32 + ip], s = sinT[row * 32 + ip];
                    float o = c * v + sgn * s * p;
                    Kb[(size_t)row * 512 + colb] = f2b(o);
#pragma unroll
                    for (int rep = 0; rep < 4; rep++) {
                        int h2 = kvh2 * 4 + rep;
                        outK[((size_t)h2 * 2048 + row) * 64 + d] = o;
                    }
                }
            }
    } else {  // ---- V: plain bf16 + repeated f32 out ----
        int cb = n0 - 2560;
#pragma unroll
        for (int i = 0; i < 4; i++)
#pragma unroll
            for (int j = 0; j < 4; j++) {
                int colb = cb + w * 64 + j * 16 + lo;
                int d = colb & 63;
                int kvh2 = colb >> 6;
#pragma unroll
                for (int r = 0; r < 4; r++) {
                    int row = m0 + i * 16 + hi * 4 + r;
                    float v = acc[i][j][r];
                    Vb[(size_t)row * 512 + colb] = f2b(v);
#pragma unroll
                    for (int rep = 0; rep < 4; rep++) {
                        int h2 = kvh2 * 4 + rep;
                        outV[((size_t)h2 * 2048 + row) * 64 + d] = v;
                    }
                }
            }
    }
#undef GSTAGE
}

// -------- output GEMM: A[M][K] bf16, BT[N][K] bf16 -> C[M][N] f32 --------
__global__ __launch_bounds__(128) void gemm_out(
    const unsigned short* __restrict__ A, const unsigned short* __restrict__ BT,
    float* __restrict__ C, int M, int N, int K) {
    __shared__ unsigned short As[3][64 * 32];
    __shared__ unsigned short Bs[3][128 * 32];
    int t = threadIdx.x;
    int w = t >> 6, lane = t & 63, lo = lane & 15, hi = lane >> 4;
    int m0 = blockIdx.y * 64, n0 = blockIdx.x * 128;
    int sr = lane >> 2;
    int scol = ((lane & 3) ^ (sr & 3)) * 8;

    const unsigned short* gA = A + (size_t)(m0 + w * 32 + sr) * K + scol;
    const unsigned short* gB = BT + (size_t)(n0 + w * 64 + sr) * K + scol;
    int rsw = (hi ^ (lo & 3)) * 8;

#define GSTAGE(buf, kk)                                                   \
    {                                                                     \
        gll16(gA + (kk), &As[buf][(w * 32) * 32]);                        \
        gll16(gA + (size_t)16 * K + (kk), &As[buf][(w * 32 + 16) * 32]);  \
        gll16(gB + (kk), &Bs[buf][(w * 64) * 32]);                        \
        gll16(gB + (size_t)16 * K + (kk), &Bs[buf][(w * 64 + 16) * 32]);  \
        gll16(gB + (size_t)32 * K + (kk), &Bs[buf][(w * 64 + 32) * 32]);  \
        gll16(gB + (size_t)48 * K + (kk), &Bs[buf][(w * 64 + 48) * 32]);  \
    }

    f32x4 acc[4][4] = {};

    GSTAGE(0, 0);
    GSTAGE(1, 32);
    int cur = 0, sb = 2;

    for (int k0 = 0; k0 < K; k0 += 32) {
        if (k0 + 64 < K) {
            CBAR(6);
            GSTAGE(sb, k0 + 64);
        } else if (k0 + 32 < K) {
            CBAR(6);
        } else {
            CBAR(0);
        }
        s16x8 af[4], bfr[4];
#pragma unroll
        for (int i = 0; i < 4; i++)
            af[i] = *(const s16x8*)&As[cur][(i * 16 + lo) * 32 + rsw];
#pragma unroll
        for (int j = 0; j < 4; j++)
            bfr[j] = *(const s16x8*)&Bs[cur][(w * 64 + j * 16 + lo) * 32 + rsw];
#pragma unroll
        for (int i = 0; i < 4; i++)
#pragma unroll
            for (int j = 0; j < 4; j++)
                acc[i][j] = __builtin_amdgcn_mfma_f32_16x16x32_bf16(
                    af[i], bfr[j], acc[i][j], 0, 0, 0);
        cur = (cur == 2) ? 0 : cur + 1;
        sb = (sb == 2) ? 0 : sb + 1;
    }
#pragma unroll
    for (int i = 0; i < 4; i++)
#pragma unroll
        for (int j = 0; j < 4; j++)
#pragma unroll
            for (int r = 0; r < 4; r++) {
                int row = m0 + i * 16 + hi * 4 + r;
                int col = n0 + w * 64 + j * 16 + lo;
                C[(size_t)row * N + col] = acc[i][j][r];
            }
#undef GSTAGE
}

// ------------- transpose bf16: in[R][C] -> out[C][R] (for V^T) -------------
__global__ __launch_bounds__(256) void transpose_bf16(
    const unsigned short* __restrict__ in, unsigned short* __restrict__ out,
    int R, int C) {
    __shared__ unsigned short tile[64][72];
    int tc = blockIdx.x * 64, tr = blockIdx.y * 64;
    int t = threadIdx.x;
    int r = t >> 2, cq = (t & 3) * 16;
    const s16x8* src = (const s16x8*)(in + (size_t)(tr + r) * C + tc + cq);
    s16x8 v0 = src[0], v1 = src[1];
    *(s16x8*)&tile[r][cq] = v0;
    *(s16x8*)&tile[r][cq + 8] = v1;
    __syncthreads();
    int oc = t >> 2, rq = (t & 3) * 16;
    s16x8 w0, w1;
#pragma unroll
    for (int j = 0; j < 8; j++) {
        w0[j] = (short)tile[rq + j][oc];
        w1[j] = (short)tile[rq + 8 + j][oc];
    }
    s16x8* dst = (s16x8*)(out + (size_t)(tc + oc) * R + tr + rq);
    dst[0] = w0; dst[1] = w1;
}

// ====================== flash attention (causal) ======================
// (unchanged from round 10/11 — 512 equal blocks, 65->37us verified)

__device__ __forceinline__ s16x8 repack_p(
    const unsigned int pk[4][2], int c, int src1, bool selB) {
    int src2 = src1 + 16;
    unsigned int tA0 = pk[2 * c][0], tA1 = pk[2 * c][1];
    unsigned int tB0 = pk[2 * c + 1][0], tB1 = pk[2 * c + 1][1];
    unsigned int a0 = __shfl((int)tA0, src1), a1 = __shfl((int)tA1, src1);
    unsigned int a2 = __shfl((int)tA0, src2), a3 = __shfl((int)tA1, src2);
    unsigned int b0 = __shfl((int)tB0, src1), b1 = __shfl((int)tB1, src1);
    unsigned int b2 = __shfl((int)tB0, src2), b3 = __shfl((int)tB1, src2);
    union { s16x8 v; unsigned int u[4]; } x;
    x.u[0] = selB ? b0 : a0;
    x.u[1] = selB ? b1 : a1;
    x.u[2] = selB ? b2 : a2;
    x.u[3] = selB ? b3 : a3;
    return x.v;
}

__global__ __launch_bounds__(256) void attn(
    const unsigned short* __restrict__ Q, const unsigned short* __restrict__ Kr,
    const unsigned short* __restrict__ Vt, unsigned short* __restrict__ Oa) {
    __shared__ unsigned short KL[3][64 * 64];
    __shared__ unsigned short VL[3][64 * 64];

    int h = blockIdx.x;
    int kvh = h >> 2;
    int p = blockIdx.y;  // 0..15 -> strips (p, 31-p)
    int t = threadIdx.x, wave = t >> 6, lane = t & 63, lo = lane & 15, hi = lane >> 4;

    int srow = wave * 16 + (lane >> 3);
    int sc = lane & 7;
    int src1 = lo + ((hi & 1) << 5);
    bool selB = hi >= 2;
    int swz = lo & 7;
    int qrel = wave * 16 + lo;

#define STAGE_KV(buf, kb)                                                          \
    {                                                                              \
        _Pragma("unroll")                                                          \
        for (int j = 0; j < 2; j++) {                                              \
            int r = srow + j * 8;                                                  \
            gll16(Kr + (size_t)((kb) * 64 + r) * 512 + kvh * 64 +                  \
                      ((sc ^ (r & 7)) * 8),                                        \
                  &KL[buf][(wave * 16 + j * 8) * 64]);                             \
            gll16(Vt + (size_t)(kvh * 64 + r) * 2048 + (kb) * 64 +                 \
                      ((sc ^ (r & 7)) * 8),                                        \
                  &VL[buf][(wave * 16 + j * 8) * 64]);                             \
        }                                                                          \
    }

#pragma unroll 1
    for (int part = 0; part < 2; ++part) {
        int s = part ? (31 - p) : p;
        int qw = s * 64 + wave * 16;

        s16x8 qf[2];
#pragma unroll
        for (int hf = 0; hf < 2; hf++)
            qf[hf] = *(const s16x8*)(Q + (size_t)(qw + lo) * 2048 +
                                     h * 64 + hf * 32 + hi * 8);

        f32x4 O[4] = {};
        float m = -1e30f, l = 0.f;

        STAGE_KV(0, 0);
        STAGE_KV(1, (s > 0 ? 1 : 0));
        int cur = 0, sb = 2;

        for (int kb = 0; kb <= s; ++kb) {
            CBAR(4);
            int nx = (kb + 2 > s) ? s : kb + 2;
            STAGE_KV(sb, nx);

            s16x8 kf[4][2];
#pragma unroll
            for (int tt = 0; tt < 4; tt++)
#pragma unroll
                for (int hf = 0; hf < 2; hf++) {
                    int ch = (hf * 4 + hi) ^ swz;
                    kf[tt][hf] = *(const s16x8*)&KL[cur][(tt * 16 + lo) * 64 + ch * 8];
                }
            s16x8 vf[2][4];
#pragma unroll
            for (int c = 0; c < 2; c++)
#pragma unroll
                for (int dt = 0; dt < 4; dt++) {
                    int ch = (c * 4 + hi) ^ swz;
                    vf[c][dt] = *(const s16x8*)&VL[cur][(dt * 16 + lo) * 64 + ch * 8];
                }

            f32x4 s0[4];
            __builtin_amdgcn_s_setprio(1);
#pragma unroll
            for (int tt = 0; tt < 4; tt++) {
                f32x4 z0 = {};
                z0 = __builtin_amdgcn_mfma_f32_16x16x32_bf16(kf[tt][0], qf[0], z0, 0, 0, 0);
                z0 = __builtin_amdgcn_mfma_f32_16x16x32_bf16(kf[tt][1], qf[1], z0, 0, 0, 0);
                s0[tt] = z0;
            }
            __builtin_amdgcn_s_setprio(0);

            if (kb == s) {
#pragma unroll
                for (int tt = 0; tt < 4; tt++)
#pragma unroll
                    for (int r = 0; r < 4; r++) {
                        int kg = tt * 16 + hi * 4 + r;
                        if (kg > qrel) s0[tt][r] = -1e30f;
                    }
            }

            float mx = s0[0][0];
#pragma unroll
            for (int tt = 0; tt < 4; tt++)
#pragma unroll
                for (int r = 0; r < 4; r++) mx = fmaxf(mx, s0[tt][r]);
            mx = fmaxf(mx, __shfl_xor(mx, 16));
            mx = fmaxf(mx, __shfl_xor(mx, 32));

            if (!__all(mx - m <= 8.0f)) {
                float mn = fmaxf(m, mx);
                float al = __builtin_amdgcn_exp2f(m - mn);
                m = mn;
                l *= al;
                float alr[4];
#pragma unroll
                for (int r = 0; r < 4; r++) alr[r] = __shfl(al, hi * 4 + r);
#pragma unroll
                for (int dt = 0; dt < 4; dt++)
#pragma unroll
                    for (int r = 0; r < 4; r++) O[dt][r] *= alr[r];
            }

            unsigned int pk[4][2];
            float rs = 0.f;
#pragma unroll
            for (int tt = 0; tt < 4; tt++) {
#pragma unroll
                for (int r = 0; r < 4; r++) {
                    float pv = __builtin_amdgcn_exp2f(s0[tt][r] - m);
                    s0[tt][r] = pv;
                    rs += pv;
                }
                unsigned int a, b;
                asm("v_cvt_pk_bf16_f32 %0, %1, %2" : "=v"(a) : "v"(s0[tt][0]), "v"(s0[tt][1]));
                asm("v_cvt_pk_bf16_f32 %0, %1, %2" : "=v"(b) : "v"(s0[tt][2]), "v"(s0[tt][3]));
                pk[tt][0] = a; pk[tt][1] = b;
            }
            rs += __shfl_xor(rs, 16);
            rs += __shfl_xor(rs, 32);
            l += rs;

#pragma unroll
            for (int c = 0; c < 2; c++) {
                s16x8 pa = repack_p(pk, c, src1, selB);
                __builtin_amdgcn_s_setprio(1);
#pragma unroll
                for (int dt = 0; dt < 4; dt++)
                    O[dt] = __builtin_amdgcn_mfma_f32_16x16x32_bf16(pa, vf[c][dt], O[dt], 0, 0, 0);
                __builtin_amdgcn_s_setprio(0);
            }

            cur = (cur == 2) ? 0 : cur + 1;
            sb = (sb == 2) ? 0 : sb + 1;
        }

        asm volatile("s_waitcnt vmcnt(0)" ::: "memory");
        __builtin_amdgcn_s_barrier();
        asm volatile("" ::: "memory");

        float inv[4];
#pragma unroll
        for (int r = 0; r < 4; r++) inv[r] = 1.0f / __shfl(l, hi * 4 + r);
        int qrow = qw + hi * 4;
#pragma unroll
        for (int dt = 0; dt < 4; dt++)
#pragma unroll
            for (int r = 0; r < 4; r++)
                Oa[(size_t)(qrow + r) * 2048 + h * 64 + dt * 16 + lo] =
                    f2b(O[dt][r] * inv[r]);
    }
}

extern "C" void kernel_launch(void* const* d_in, const int* in_sizes, int n_in,
                              void* d_out, int out_size, void* d_ws, size_t ws_size,
                              hipStream_t stream) {
    const float* x  = (const float*)d_in[0];
    const float* R  = (const float*)d_in[1];
    // d_in[2] = mask: unused (causal mask applied analytically)
    const float* wq = (const float*)d_in[3];
    const float* wk = (const float*)d_in[4];
    const float* wv = (const float*)d_in[5];
    const float* wo = (const float*)d_in[6];

    float* out0 = (float*)d_out;
    float* outK = out0 + (size_t)2048 * 2048;
    float* outV = outK + (size_t)32 * 2048 * 64;

    char* ws = (char*)d_ws;
    unsigned short* BTall = (unsigned short*)(ws);               // 12 MB [3072][2048]
    unsigned short* woT = (unsigned short*)(ws + 12582912);      // 8 MB
    unsigned short* Qb  = (unsigned short*)(ws + 20971520);      // 8 MB
    unsigned short* Kb  = (unsigned short*)(ws + 29360128);      // 2 MB
    unsigned short* Vb  = (unsigned short*)(ws + 31457280);      // 2 MB
    unsigned short* VtT = (unsigned short*)(ws + 33554432);      // 2 MB [512][2048]
    unsigned short* Ob  = (unsigned short*)(ws + 35651584);      // 8 MB
    float* cosT = (float*)(ws + 44040192);                       // 256 KB
    float* sinT = (float*)(ws + 44302336);                       // 256 KB
    unsigned short* xb  = (unsigned short*)(ws + 44564480);      // 8 MB

    prep<<<dim3(32, 32, 6), 256, 0, stream>>>(x, R, wq, wk, wv, wo, xb, BTall,
                                              woT, cosT, sinT);

    gemm_qkv<<<dim3(24, 32), 128, 0, stream>>>(xb, BTall, Qb, Kb, Vb, cosT, sinT, outK, outV);

    transpose_bf16<<<dim3(8, 32), 256, 0, stream>>>(Vb, VtT, 2048, 512);

    attn<<<dim3(32, 16), 256, 0, stream>>>(Qb, Kb, VtT, Ob);

    gemm_out<<<dim3(16, 32), 128, 0, stream>>>(Ob, woT, out0, 2048, 2048, 2048);
}